// Round 2
// baseline (214.711 us; speedup 1.0000x reference)
//
#include <hip/hip_runtime.h>
#include <hip/hip_bf16.h>
#include <hip/hip_fp16.h>
#include <stdint.h>

using bf16 = __hip_bfloat16;

typedef __bf16    bf16x8 __attribute__((ext_vector_type(8)));
typedef float     floatx4 __attribute__((ext_vector_type(4)));
typedef _Float16  f16x2 __attribute__((ext_vector_type(2)));
typedef _Float16  f16x8 __attribute__((ext_vector_type(8)));

typedef __attribute__((address_space(3))) void as3_void;
typedef __attribute__((address_space(1))) void as1_void;

// async global->LDS, 16B/lane; LDS dest is wave-uniform base + lane*16.
#define GLD_LDS16(gp, lp) \
  __builtin_amdgcn_global_load_lds((as1_void*)(uintptr_t)(gp), (as3_void*)(uintptr_t)(lp), 16, 0, 0)

#define FENCE() asm volatile("" ::: "memory")
#define BAR()   do { FENCE(); __builtin_amdgcn_s_barrier(); FENCE(); } while (0)
#define WAITL0() do { asm volatile("s_waitcnt lgkmcnt(0)" ::: "memory"); \
                      __builtin_amdgcn_sched_barrier(0); } while (0)

// ---------------------------------------------------------------------------
// prep: blocks 0..1023 transpose W (fp32 [k][n] -> bf16 [n][k]); blocks
// 1024..3071 convert x fp32->bf16 (32 B stores/thread).
// ---------------------------------------------------------------------------
__global__ __launch_bounds__(256) void prep_kernel(
    const float* __restrict__ x,
    const float* __restrict__ Wq, const float* __restrict__ Wk,
    const float* __restrict__ Wv, const float* __restrict__ Wo,
    bf16* __restrict__ xbf, bf16* __restrict__ WTqkv, bf16* __restrict__ WoT) {
  __shared__ float tile[64 * 68];
  const int blk = blockIdx.x;
  const int tid = threadIdx.x;
  if (blk < 1024) {
    const int z = blk >> 8, t = blk & 255;
    const float* src = (z == 0) ? Wq : (z == 1) ? Wk : (z == 2) ? Wv : Wo;
    bf16* dst = (z < 3) ? (WTqkv + (size_t)z * 1024 * 1024) : WoT;
    const int nbase = (t & 15) * 64, kbase = (t >> 4) * 64;
    const int r1 = tid >> 4, c1 = tid & 15;
#pragma unroll
    for (int it = 0; it < 4; ++it) {
      const int row = r1 + it * 16;
      const float4 v = *(const float4*)(src + (size_t)(kbase + row) * 1024 + nbase + c1 * 4);
      *(float4*)(tile + row * 68 + c1 * 4) = v;
    }
    __syncthreads();
    const int c2 = tid & 7, n2 = tid >> 3;
#pragma unroll
    for (int it2 = 0; it2 < 2; ++it2) {
      const int n = n2 + it2 * 32;
      bf16 o[8];
#pragma unroll
      for (int s = 0; s < 8; ++s) o[s] = (bf16)tile[(8 * c2 + s) * 68 + n];
      *(uint4*)(dst + (size_t)(nbase + n) * 1024 + kbase + 8 * c2) = *(const uint4*)o;
    }
  } else {
    const size_t basei = ((size_t)(blk - 1024) * 256 + tid) * 16;
#pragma unroll
    for (int h = 0; h < 2; ++h) {
      const float4 a = *(const float4*)(x + basei + h * 8);
      const float4 b = *(const float4*)(x + basei + h * 8 + 4);
      bf16 o[8] = {(bf16)a.x, (bf16)a.y, (bf16)a.z, (bf16)a.w,
                   (bf16)b.x, (bf16)b.y, (bf16)b.z, (bf16)b.w};
      *(uint4*)(xbf + basei + h * 8) = *(const uint4*)o;
    }
  }
}

// ---------------------------------------------------------------------------
// QKV GEMM — 256x256 8-phase schedule (T2+T3+T4+T5 port, m201 template).
// 512 thr = 8 waves (2M x 4N); per-wave 128x64 out = acc[8][4] f32x4.
// BK=64, 2 K-tiles per iter, 8 phases/iter; one 16KB half-tile staged per
// phase via global_load_lds w=16 (linear LDS dest, inverse-swizzled global
// src); counted vmcnt(6) only at phases 4/8. XOR chunk swizzle (^ row&7)
// on LDS reads kills the stride-128B bank conflict.
// A (8192,1024) bf16 row-major; Bt (3072,1024) bf16 (W^T); out f16 QKV
// scattered to (B,H,N,DH), which = n>>10.
// ---------------------------------------------------------------------------
#define SA8(buf, h, kt) do { \
    GLD_LDS16(A + abase + (uint64_t)((h) * 131072) + (uint64_t)(kt) * 64, \
              (char*)(&As[(buf)][0]) + (h) * 16384 + ldst); \
    GLD_LDS16(A + abase + (uint64_t)((h) * 131072 + 65536) + (uint64_t)(kt) * 64, \
              (char*)(&As[(buf)][0]) + (h) * 16384 + 8192 + ldst); \
  } while (0)

#define SB8(buf, h, kt) do { \
    GLD_LDS16(Bt + bbase + (uint64_t)((h) * 131072) + (uint64_t)(kt) * 64, \
              (char*)(&Bs[(buf)][0]) + (h) * 16384 + ldst); \
    GLD_LDS16(Bt + bbase + (uint64_t)((h) * 131072 + 65536) + (uint64_t)(kt) * 64, \
              (char*)(&Bs[(buf)][0]) + (h) * 16384 + 8192 + ldst); \
  } while (0)

#define RDA8(buf, up) do { \
    const char* _p = (const char*)(&As[(buf)][0]) + arow0 + (up); \
    af[0][0] = *(const bf16x8*)(_p + 0 * 2048 + pcb0); \
    af[0][1] = *(const bf16x8*)(_p + 0 * 2048 + pcb1); \
    af[1][0] = *(const bf16x8*)(_p + 1 * 2048 + pcb0); \
    af[1][1] = *(const bf16x8*)(_p + 1 * 2048 + pcb1); \
    af[2][0] = *(const bf16x8*)(_p + 2 * 2048 + pcb0); \
    af[2][1] = *(const bf16x8*)(_p + 2 * 2048 + pcb1); \
    af[3][0] = *(const bf16x8*)(_p + 3 * 2048 + pcb0); \
    af[3][1] = *(const bf16x8*)(_p + 3 * 2048 + pcb1); \
  } while (0)

#define RDB8(buf) do { \
    const char* _p = (const char*)(&Bs[(buf)][0]) + brow0; \
    bf[0][0] = *(const bf16x8*)(_p + 0 * 2048 + pcb0); \
    bf[0][1] = *(const bf16x8*)(_p + 0 * 2048 + pcb1); \
    bf[1][0] = *(const bf16x8*)(_p + 1 * 2048 + pcb0); \
    bf[1][1] = *(const bf16x8*)(_p + 1 * 2048 + pcb1); \
    bf[2][0] = *(const bf16x8*)(_p + 2 * 2048 + pcb0); \
    bf[2][1] = *(const bf16x8*)(_p + 2 * 2048 + pcb1); \
    bf[3][0] = *(const bf16x8*)(_p + 3 * 2048 + pcb0); \
    bf[3][1] = *(const bf16x8*)(_p + 3 * 2048 + pcb1); \
  } while (0)

#define MMQ8(ab, nb) do { \
    _Pragma("unroll") for (int _i = 0; _i < 4; ++_i) \
      _Pragma("unroll") for (int _j = 0; _j < 2; ++_j) \
        _Pragma("unroll") for (int _kc = 0; _kc < 2; ++_kc) \
          acc[(ab) + _i][(nb) + _j] = __builtin_amdgcn_mfma_f32_16x16x32_bf16( \
              af[_i][_kc], bf[(nb) + _j][_kc], acc[(ab) + _i][(nb) + _j], 0, 0, 0); \
  } while (0)

__global__ __launch_bounds__(512, 2) void gemm_qkv_8ph(
    const bf16* __restrict__ A, const bf16* __restrict__ Bt,
    const float* __restrict__ b0, const float* __restrict__ b1, const float* __restrict__ b2,
    __half* __restrict__ out0, __half* __restrict__ out1, __half* __restrict__ out2) {
  const int t    = threadIdx.x;
  const int m0   = blockIdx.x * 256;
  const int n0   = blockIdx.y * 256;
  const int lane = t & 63;
  const int wave = t >> 6;      // 0..7
  const int wm   = wave >> 2;   // 0..1 -> 128-row half
  const int wn   = wave & 3;    // 0..3 -> 64-col strip
  const int quad = lane >> 4;
  const int l16  = lane & 15;

  __shared__ alignas(16) bf16 As[2][256 * 64];  // 2 x 32 KiB
  __shared__ alignas(16) bf16 Bs[2][256 * 64];  // 2 x 32 KiB  (128 KiB total)

  // staging: thread t writes linear LDS slot (row = 64j + t>>3, chunk = t&7);
  // global source pre-swizzled: chunk ^= row&7 (involution, matches read).
  const int srt = t >> 3;
  const int sct = ((t & 7) ^ (srt & 7)) << 3;  // element offset in K-tile
  const uint64_t abase = (uint64_t)(m0 + srt) * 1024 + sct;
  const uint64_t bbase = (uint64_t)(n0 + srt) * 1024 + sct;
  const int ldst = t * 16;

  // frag-read addressing (row&7 == l16&7 for all frag rows)
  const int arow0 = (wm * 128 + l16) * 128;  // bytes
  const int brow0 = (wn * 64 + l16) * 128;
  const int pcb0  = ((quad) ^ (l16 & 7)) << 4;
  const int pcb1  = ((4 + quad) ^ (l16 & 7)) << 4;

  floatx4 acc[8][4];
#pragma unroll
  for (int i = 0; i < 8; ++i)
#pragma unroll
    for (int j = 0; j < 4; ++j) {
      floatx4 z = {0.f, 0.f, 0.f, 0.f};
      acc[i][j] = z;
    }
  bf16x8 af[4][2], bf[4][2];

  // prologue: T0 (4 halves -> buf0), T1 (B0,B1,A0 -> buf1) = 7 halves.
  SB8(0, 0, 0); SB8(0, 1, 0); SA8(0, 0, 0); SA8(0, 1, 0);
  SB8(1, 0, 1); SB8(1, 1, 1); SA8(1, 0, 1);
  asm volatile("s_waitcnt vmcnt(6)" ::: "memory");  // T0 fully arrived
  BAR();

  for (int i = 0; i < 8; ++i) {
    const int t1 = 2 * i + 1;
    const int t2 = 2 * i + 2;
    const int t3 = 2 * i + 3;
    const bool pf = (i < 7);

    // p1: read buf0 A[m0-3]+B[all]; issue T1.A1 (buf1.Ahalf1 free since p7')
    RDA8(0, 0);
    RDB8(0);
    SA8(1, 1, t1);
    BAR(); WAITL0();
    __builtin_amdgcn_s_setprio(1); MMQ8(0, 0); __builtin_amdgcn_s_setprio(0);
    BAR();

    // p2: issue T2.B0 (buf0.B free after p1)
    if (pf) SB8(0, 0, t2);
    BAR();
    __builtin_amdgcn_s_setprio(1); MMQ8(0, 2); __builtin_amdgcn_s_setprio(0);
    BAR();

    // p3: read buf0 A[m4-7]; issue T2.B1
    RDA8(0, 8192);
    if (pf) SB8(0, 1, t2);
    BAR(); WAITL0();
    __builtin_amdgcn_s_setprio(1); MMQ8(4, 0); __builtin_amdgcn_s_setprio(0);
    BAR();

    // p4: issue T2.A0 (buf0.A free after p3); wait T1 complete (<=3 halves out)
    if (pf) SA8(0, 0, t2);
    BAR();
    __builtin_amdgcn_s_setprio(1); MMQ8(4, 2); __builtin_amdgcn_s_setprio(0);
    if (pf) { asm volatile("s_waitcnt vmcnt(6)" ::: "memory"); }
    else    { asm volatile("s_waitcnt vmcnt(0)" ::: "memory"); }
    BAR();

    // p5: read buf1 A[m0-3]+B[all]; issue T2.A1
    RDA8(1, 0);
    RDB8(1);
    if (pf) SA8(0, 1, t2);
    BAR(); WAITL0();
    __builtin_amdgcn_s_setprio(1); MMQ8(0, 0); __builtin_amdgcn_s_setprio(0);
    BAR();

    // p6: issue T3.B0 (buf1.B free after p5)
    if (pf) SB8(1, 0, t3);
    BAR();
    __builtin_amdgcn_s_setprio(1); MMQ8(0, 2); __builtin_amdgcn_s_setprio(0);
    BAR();

    // p7: read buf1 A[m4-7]; issue T3.B1
    RDA8(1, 8192);
    if (pf) SB8(1, 1, t3);
    BAR(); WAITL0();
    __builtin_amdgcn_s_setprio(1); MMQ8(4, 0); __builtin_amdgcn_s_setprio(0);
    BAR();

    // p8: issue T3.A0; wait T2 complete
    if (pf) SA8(1, 0, t3);
    BAR();
    __builtin_amdgcn_s_setprio(1); MMQ8(4, 2); __builtin_amdgcn_s_setprio(0);
    if (pf) { asm volatile("s_waitcnt vmcnt(6)" ::: "memory"); }
    BAR();
  }

  // epilogue: bias + f16 scatter to (B,H,N,DH)
#pragma unroll
  for (int mi = 0; mi < 8; ++mi) {
#pragma unroll
    for (int ni = 0; ni < 4; ++ni) {
#pragma unroll
      for (int r = 0; r < 4; ++r) {
        const int m = m0 + wm * 128 + mi * 16 + quad * 4 + r;
        const int n = n0 + wn * 64 + ni * 16 + l16;
        float v = acc[mi][ni][r];
        const int which = n >> 10;
        const int c = n & 1023;
        const float* bp = (which == 0) ? b0 : (which == 1) ? b1 : b2;
        __half* op      = (which == 0) ? out0 : (which == 1) ? out1 : out2;
        v += bp[c];
        const int h = c >> 6, dh = c & 63;
        const int bb = m >> 11, seq = m & 2047;
        op[(uint64_t)(bb * 16 + h) * 131072 + (uint64_t)seq * 64 + dh] = (__half)v;
      }
    }
  }
}

// ---------------------------------------------------------------------------
// GEMM 128x128 (m97 structure) — kept for the output projection only.
// MODE 1: A (B,H,N,DH) head-layout bf16; fout=acc+b0 fp32.
// ---------------------------------------------------------------------------
template <int MODE>
__global__ __launch_bounds__(256) void gemm_bt_kernel(
    const bf16* __restrict__ A, const bf16* __restrict__ Bt,
    const float* __restrict__ b0, const float* __restrict__ b1, const float* __restrict__ b2,
    __half* __restrict__ out0, __half* __restrict__ out1, __half* __restrict__ out2,
    float* __restrict__ fout) {
  const int tid  = threadIdx.x;
  const int m0   = blockIdx.x * 128;
  const int n0   = blockIdx.y * 128;
  const int lane = tid & 63;
  const int wave = tid >> 6;
  const int wr   = (wave >> 1) * 64;
  const int wc   = (wave & 1) * 64;
  const int quad = lane >> 4;
  const int l16  = lane & 15;

  __shared__ alignas(16) bf16 As[128 * 64];
  __shared__ alignas(16) bf16 Bs[128 * 64];

  const int srow = tid >> 3;
  const int cg   = (tid & 7) ^ (srow & 7);
  uint64_t aoff;
  if (MODE == 0) {
    aoff = (uint64_t)(m0 + srow) * 1024 + cg * 8;
  } else {
    const int b = m0 >> 11, seq0 = m0 & 2047;
    aoff = (uint64_t)b * 2097152 + (uint64_t)(seq0 + srow) * 64 + cg * 8;
  }
  const uint64_t boff = (uint64_t)(n0 + srow) * 1024 + cg * 8;

  floatx4 acc[4][4];
#pragma unroll
  for (int i = 0; i < 4; ++i)
#pragma unroll
    for (int j = 0; j < 4; ++j) {
      floatx4 z = {0.f, 0.f, 0.f, 0.f};
      acc[i][j] = z;
    }

  for (int k0 = 0; k0 < 1024; k0 += 64) {
    __syncthreads();
#pragma unroll
    for (int it = 0; it < 4; ++it) {
      if (MODE == 0)
        GLD_LDS16(A + aoff + (uint64_t)it * 32768 + k0, (char*)As + it * 4096 + tid * 16);
      else
        GLD_LDS16(A + aoff + (uint64_t)it * 2048 + (uint64_t)(k0 >> 6) * 131072,
                  (char*)As + it * 4096 + tid * 16);
      GLD_LDS16(Bt + boff + (uint64_t)it * 32768 + k0, (char*)Bs + it * 4096 + tid * 16);
    }
    __syncthreads();

#pragma unroll
    for (int kc = 0; kc < 2; ++kc) {
      bf16x8 af[4], bfr[4];
#pragma unroll
      for (int i = 0; i < 4; ++i) {
        const int mrow = wr + i * 16 + l16;
        const int pca  = (kc * 4 + quad) ^ (mrow & 7);
        af[i] = *(const bf16x8*)(As + mrow * 64 + pca * 8);
        const int nrow = wc + i * 16 + l16;
        const int pcb  = (kc * 4 + quad) ^ (nrow & 7);
        bfr[i] = *(const bf16x8*)(Bs + nrow * 64 + pcb * 8);
      }
#pragma unroll
      for (int i = 0; i < 4; ++i)
#pragma unroll
        for (int j = 0; j < 4; ++j)
          acc[i][j] = __builtin_amdgcn_mfma_f32_16x16x32_bf16(af[i], bfr[j], acc[i][j], 0, 0, 0);
    }
  }

#pragma unroll
  for (int i = 0; i < 4; ++i) {
#pragma unroll
    for (int j = 0; j < 4; ++j) {
#pragma unroll
      for (int r = 0; r < 4; ++r) {
        const int m = m0 + wr + i * 16 + quad * 4 + r;
        const int n = n0 + wc + j * 16 + l16;
        float v = acc[i][j][r];
        if (MODE == 0) {
          const int which = n >> 10;
          const int c = n & 1023;
          const float* bp = (which == 0) ? b0 : (which == 1) ? b1 : b2;
          __half* op      = (which == 0) ? out0 : (which == 1) ? out1 : out2;
          v += bp[c];
          const int h = c >> 6, dh = c & 63;
          const int bb = m >> 11, seq = m & 2047;
          op[(uint64_t)(bb * 16 + h) * 131072 + (uint64_t)seq * 64 + dh] = (__half)v;
        } else {
          fout[(uint64_t)m * 1024 + n] = v + b0[n];
        }
      }
    }
  }
}

// ---------------------------------------------------------------------------
// Dilated attention v6 - MFMA (unchanged).
// ---------------------------------------------------------------------------
#define RMAXA 32
#define VTS 176       // VT col stride (halves); 16w+32+c*32+quad*8+7 <= 175
#define PS  104       // P row stride (halves)

__global__ __launch_bounds__(256) void dilated_attn_mfma_kernel(
    const __half* __restrict__ Q, const __half* __restrict__ K, const __half* __restrict__ V,
    bf16* __restrict__ attn_out, const int* __restrict__ kptr, const int* __restrict__ dptr) {
  const int tid  = threadIdx.x;
  const int wave = tid >> 6, lane = tid & 63;
  const int quad = lane >> 4, l16 = lane & 15;
  const int bh = blockIdx.x >> 5;       // 32 query-blocks of 64 per (b,h)
  const int Q0 = (blockIdx.x & 31) * 64;
  const int kk  = kptr[0];
  const int dil = dptr[0];
  const int R   = kk * dil;
  const size_t base = (size_t)bh * 2048 * 64;
  const _Float16* Qh = (const _Float16*)Q;
  const _Float16* Kh = (const _Float16*)K;
  const _Float16* Vh = (const _Float16*)V;

  __shared__ alignas(16) _Float16 smem[64 * VTS + 4 * 16 * PS];  // 35840 B
  _Float16* VT = smem;
  _Float16* Pw = smem + 64 * VTS + wave * 16 * PS;

  const bool fast = (R <= RMAXA) && (dil >= 1);

  if (fast) {
    // zero-fill VT + P (guards / pad cols must be 0, not stale/NaN bits)
    {
      const int nch = (64 * VTS + 4 * 16 * PS) / 8;
      const f16x8 z = {0, 0, 0, 0, 0, 0, 0, 0};
      for (int c = tid; c < nch; c += 256) ((f16x8*)smem)[c] = z;
    }
    __syncthreads();

    // stage V transposed: VT[dh][col], col = j - (Q0-R) + 32
    const int jlo = Q0 - R;  // unclamped
    const int lo = (jlo > 0) ? jlo : 0;
    const int hi = (Q0 + 63 + R < 2047) ? Q0 + 63 + R : 2047;
    const int nrows = hi - lo + 1;
    for (int idx = tid; idx < nrows * 8; idx += 256) {
      const int r = idx >> 3, c = idx & 7;
      const int j = lo + r;
      const f16x8 v = *(const f16x8*)(Vh + base + (size_t)j * 64 + c * 8);
      const int col = j - jlo + 32;
#pragma unroll
      for (int s = 0; s < 8; ++s) VT[(c * 8 + s) * VTS + col] = v[s];
    }
    __syncthreads();

    const int i0 = Q0 + wave * 16;
    // Q A-frags (2 k-chunks of 32 over DH=64)
    const f16x8 a0 = *(const f16x8*)(Qh + base + (size_t)(i0 + l16) * 64 + quad * 8);
    const f16x8 a1 = *(const f16x8*)(Qh + base + (size_t)(i0 + l16) * 64 + 32 + quad * 8);

    const int nkt = (16 + 2 * R + 15) >> 4;   // key tiles of 16
    const int jw0 = i0 - R;                   // wave key-window start
    float lsum[4] = {0.f, 0.f, 0.f, 0.f};
    const floatx4 zf = {0.f, 0.f, 0.f, 0.f};

    for (int kt = 0; kt < nkt; ++kt) {
      const int j0 = jw0 + 16 * kt;
      const int jn = j0 + l16;                        // this lane's key (B n)
      const int jc = (jn < 0) ? 0 : (jn > 2047 ? 2047 : jn);
      const f16x8 b0 = *(const f16x8*)(Kh + base + (size_t)jc * 64 + quad * 8);
      const f16x8 b1 = *(const f16x8*)(Kh + base + (size_t)jc * 64 + 32 + quad * 8);
      floatx4 s4 = __builtin_amdgcn_mfma_f32_16x16x32_f16(a0, b0, zf, 0, 0, 0);
      s4 = __builtin_amdgcn_mfma_f32_16x16x32_f16(a1, b1, s4, 0, 0, 0);
#pragma unroll
      for (int r = 0; r < 4; ++r) {
        const int m = quad * 4 + r;
        const int d = jn - (i0 + m);
        const bool valid = ((unsigned)jn < 2048u) && (d >= -R) && (d <= R) && (d % dil == 0);
        const float pe = valid ? __expf(s4[r] * 0.125f) : 0.f;
        lsum[r] += pe;
        Pw[m * PS + kt * 16 + l16] = (_Float16)pe;
      }
    }
    // row sums: reduce across the 16 lanes of each quad
#pragma unroll
    for (int r = 0; r < 4; ++r) {
      lsum[r] += __shfl_xor(lsum[r], 1);
      lsum[r] += __shfl_xor(lsum[r], 2);
      lsum[r] += __shfl_xor(lsum[r], 4);
      lsum[r] += __shfl_xor(lsum[r], 8);
    }

    // PV: o[t](16 x 16dh) accumulated f32; A = P[m=lane&15][k], B = VT
    const int nkc = (nkt * 16 + 31) >> 5;     // 32-wide k-chunks
    floatx4 o[4] = {zf, zf, zf, zf};
    const int vbase = 16 * wave + 32;         // VT col of k_rel = 0
    for (int c = 0; c < nkc; ++c) {
      const f16x8 pa = *(const f16x8*)(Pw + l16 * PS + c * 32 + quad * 8);
#pragma unroll
      for (int t = 0; t < 4; ++t) {
        const f16x8 vb = *(const f16x8*)(VT + (t * 16 + l16) * VTS + vbase + c * 32 + quad * 8);
        o[t] = __builtin_amdgcn_mfma_f32_16x16x32_f16(pa, vb, o[t], 0, 0, 0);
      }
    }

    // normalize + stage O into Pw ([m][dh], stride PS), then coalesced store
#pragma unroll
    for (int t = 0; t < 4; ++t) {
#pragma unroll
      for (int r = 0; r < 4; ++r)
        Pw[(quad * 4 + r) * PS + t * 16 + l16] = (_Float16)(o[t][r] / lsum[r]);
    }
    const int orow = lane >> 2, oseg = lane & 3;
#pragma unroll
    for (int hseg = 0; hseg < 2; ++hseg) {
      const f16x8 ov = *(const f16x8*)(Pw + orow * PS + oseg * 16 + hseg * 8);
      bf16 ob[8];
#pragma unroll
      for (int s = 0; s < 8; ++s) ob[s] = (bf16)(float)ov[s];
      *(uint4*)(attn_out + base + (size_t)(i0 + orow) * 64 + oseg * 16 + hseg * 8) =
          *(const uint4*)ob;
    }
    return;
  }

  // ---- fallback: rarely taken; plain per-lane scalar loop ----
  if (tid < 64) {
    const int i = Q0 + tid;
    float l = 0.f;
    float oacc[64];
#pragma unroll
    for (int u = 0; u < 64; ++u) oacc[u] = 0.f;
    float qv[64];
#pragma unroll
    for (int u = 0; u < 64; ++u) qv[u] = (float)Qh[base + (size_t)i * 64 + u];
    for (int t = -kk; t <= kk; ++t) {
      const int j = i + (int)((long long)t * dil);
      if (j < 0 || j >= 2048) continue;
      float s = 0.f;
      for (int u = 0; u < 64; ++u) s += qv[u] * (float)Kh[base + (size_t)j * 64 + u];
      const float pe = __expf(s * 0.125f);
      l += pe;
      for (int u = 0; u < 64; ++u) oacc[u] += pe * (float)Vh[base + (size_t)j * 64 + u];
    }
    for (int u = 0; u < 64; ++u)
      attn_out[base + (size_t)i * 64 + u] = (bf16)(oacc[u] / l);
  }
}

// ---------------------------------------------------------------------------
extern "C" void kernel_launch(void* const* d_in, const int* in_sizes, int n_in,
                              void* d_out, int out_size, void* d_ws, size_t ws_size,
                              hipStream_t stream) {
  const float* x  = (const float*)d_in[0];
  const float* Wq = (const float*)d_in[1];
  const float* bq = (const float*)d_in[2];
  const float* Wk = (const float*)d_in[3];
  const float* bk = (const float*)d_in[4];
  const float* Wv = (const float*)d_in[5];
  const float* bv = (const float*)d_in[6];
  const float* Wo = (const float*)d_in[7];
  const float* bo = (const float*)d_in[8];
  const int* kp   = (const int*)d_in[9];
  const int* dp   = (const int*)d_in[10];
  float* out = (float*)d_out;

  bf16*   xbf   = (bf16*)d_ws;                   // 8388608  (B,N,D) bf16
  bf16*   WTqkv = xbf + 8388608;                 // 3072*1024 bf16
  bf16*   WoT   = WTqkv + 3072 * 1024;           // 1024*1024 bf16
  __half* qbuf  = (__half*)(WoT + 1024 * 1024);  // 8388608 (B,H,N,DH) f16
  __half* kbuf  = qbuf + 8388608;
  __half* vbuf  = kbuf + 8388608;
  bf16*   attnH = xbf;                           // alias: (B,H,N,DH) bf16

  prep_kernel<<<dim3(3072), 256, 0, stream>>>(x, Wq, Wk, Wv, Wo, xbf, WTqkv, WoT);

  gemm_qkv_8ph<<<dim3(32, 12), 512, 0, stream>>>(xbf, WTqkv, bq, bk, bv,
                                                 qbuf, kbuf, vbuf);

  dilated_attn_mfma_kernel<<<dim3(2048), 256, 0, stream>>>(qbuf, kbuf, vbuf, attnH, kp, dp);

  gemm_bt_kernel<1><<<dim3(64, 8), 256, 0, stream>>>(attnH, WoT, bo, nullptr, nullptr,
                                                     nullptr, nullptr, nullptr, out);
}

// Round 6
// 208.237 us; speedup vs baseline: 1.0311x; 1.0311x over previous
//
#include <hip/hip_runtime.h>
#include <hip/hip_bf16.h>
#include <hip/hip_fp16.h>
#include <stdint.h>

using bf16 = __hip_bfloat16;

typedef __bf16    bf16x8 __attribute__((ext_vector_type(8)));
typedef float     floatx4 __attribute__((ext_vector_type(4)));
typedef _Float16  f16x8 __attribute__((ext_vector_type(8)));

typedef __attribute__((address_space(3))) void as3_void;
typedef __attribute__((address_space(1))) void as1_void;

// async global->LDS, 16B/lane; LDS dest is wave-uniform base + lane*16.
#define GLD_LDS16(gp, lp) \
  __builtin_amdgcn_global_load_lds((as1_void*)(uintptr_t)(gp), (as3_void*)(uintptr_t)(lp), 16, 0, 0)

#define FENCE() asm volatile("" ::: "memory")
#define BAR()   do { FENCE(); __builtin_amdgcn_s_barrier(); FENCE(); } while (0)
#define WAITL0() do { asm volatile("s_waitcnt lgkmcnt(0)" ::: "memory"); \
                      __builtin_amdgcn_sched_barrier(0); } while (0)

// ---------------------------------------------------------------------------
// prep: blocks 0..1023 transpose W (fp32 [k][n] -> bf16 [n][k]); blocks
// 1024..3071 convert x fp32->bf16 (32 B stores/thread).
// ---------------------------------------------------------------------------
__global__ __launch_bounds__(256) void prep_kernel(
    const float* __restrict__ x,
    const float* __restrict__ Wq, const float* __restrict__ Wk,
    const float* __restrict__ Wv, const float* __restrict__ Wo,
    bf16* __restrict__ xbf, bf16* __restrict__ WTqkv, bf16* __restrict__ WoT) {
  __shared__ float tile[64 * 68];
  const int blk = blockIdx.x;
  const int tid = threadIdx.x;
  if (blk < 1024) {
    const int z = blk >> 8, t = blk & 255;
    const float* src = (z == 0) ? Wq : (z == 1) ? Wk : (z == 2) ? Wv : Wo;
    bf16* dst = (z < 3) ? (WTqkv + (size_t)z * 1024 * 1024) : WoT;
    const int nbase = (t & 15) * 64, kbase = (t >> 4) * 64;
    const int r1 = tid >> 4, c1 = tid & 15;
#pragma unroll
    for (int it = 0; it < 4; ++it) {
      const int row = r1 + it * 16;
      const float4 v = *(const float4*)(src + (size_t)(kbase + row) * 1024 + nbase + c1 * 4);
      *(float4*)(tile + row * 68 + c1 * 4) = v;
    }
    __syncthreads();
    const int c2 = tid & 7, n2 = tid >> 3;
#pragma unroll
    for (int it2 = 0; it2 < 2; ++it2) {
      const int n = n2 + it2 * 32;
      bf16 o[8];
#pragma unroll
      for (int s = 0; s < 8; ++s) o[s] = (bf16)tile[(8 * c2 + s) * 68 + n];
      *(uint4*)(dst + (size_t)(nbase + n) * 1024 + kbase + 8 * c2) = *(const uint4*)o;
    }
  } else {
    const size_t basei = ((size_t)(blk - 1024) * 256 + tid) * 16;
#pragma unroll
    for (int h = 0; h < 2; ++h) {
      const float4 a = *(const float4*)(x + basei + h * 8);
      const float4 b = *(const float4*)(x + basei + h * 8 + 4);
      bf16 o[8] = {(bf16)a.x, (bf16)a.y, (bf16)a.z, (bf16)a.w,
                   (bf16)b.x, (bf16)b.y, (bf16)b.z, (bf16)b.w};
      *(uint4*)(xbf + basei + h * 8) = *(const uint4*)o;
    }
  }
}

// ---------------------------------------------------------------------------
// QKV GEMM — 8-phase schedule, BM=256 x BN=192, BK=64.
// grid 32x16 = 512 blocks = EXACTLY 2 rounds on 256 CUs (fixes R2's 1.5-round
// quantization loss). 512 thr = 8 waves (2M x 4N); per-wave 128x48 out =
// acc[8][3]. LDS 112 KiB dbuf: A = 4 units of 8KB/tile, B = 3 units.
// Stage slots sit one phase after each unit's last read; counted vmcnt(5)
// at p4/p8 (5 younger loads outstanding when prev tile must be complete).
// XOR chunk swizzle (^row&7) via inverse-swizzled global source.
// Output: row-major f16 qkv[8192][3072] (+bias), coalesced via LDS restage.
// ---------------------------------------------------------------------------
#define SAU(bufi, u, kt) \
  GLD_LDS16(A + abase + (uint64_t)(u) * 65536 + (uint64_t)(kt) * 64, \
            (char*)(&As[bufi][0]) + (u) * 8192 + ldst)
#define SBU(bufi, u, kt) \
  GLD_LDS16(Bt + bbase + (uint64_t)(u) * 65536 + (uint64_t)(kt) * 64, \
            (char*)(&Bs[bufi][0]) + (u) * 8192 + ldst)

#define RDA2(bufi, mb) do { \
    const char* _p = (const char*)(&As[bufi][0]) + (wm * 128 + (mb) * 16 + l16) * 128; \
    af[0][0] = *(const bf16x8*)(_p + pcb0); \
    af[0][1] = *(const bf16x8*)(_p + pcb1); \
    af[1][0] = *(const bf16x8*)(_p + 2048 + pcb0); \
    af[1][1] = *(const bf16x8*)(_p + 2048 + pcb1); \
  } while (0)

#define RDB3(bufi) do { \
    const char* _p = (const char*)(&Bs[bufi][0]) + (wn * 48 + l16) * 128; \
    bfr[0][0] = *(const bf16x8*)(_p + pcb0); \
    bfr[0][1] = *(const bf16x8*)(_p + pcb1); \
    bfr[1][0] = *(const bf16x8*)(_p + 2048 + pcb0); \
    bfr[1][1] = *(const bf16x8*)(_p + 2048 + pcb1); \
    bfr[2][0] = *(const bf16x8*)(_p + 4096 + pcb0); \
    bfr[2][1] = *(const bf16x8*)(_p + 4096 + pcb1); \
  } while (0)

#define MMQ12(mb) do { \
    _Pragma("unroll") for (int _i = 0; _i < 2; ++_i) \
      _Pragma("unroll") for (int _j = 0; _j < 3; ++_j) \
        _Pragma("unroll") for (int _k = 0; _k < 2; ++_k) \
          acc[(mb) + _i][_j] = __builtin_amdgcn_mfma_f32_16x16x32_bf16( \
              af[_i][_k], bfr[_j][_k], acc[(mb) + _i][_j], 0, 0, 0); \
  } while (0)

__global__ __launch_bounds__(512, 2) void gemm_qkv_8ph(
    const bf16* __restrict__ A, const bf16* __restrict__ Bt,
    const float* __restrict__ b0, const float* __restrict__ b1, const float* __restrict__ b2,
    __half* __restrict__ qkv) {
  const int t    = threadIdx.x;
  const int m0   = blockIdx.x * 256;
  const int n0   = blockIdx.y * 192;
  const int lane = t & 63;
  const int wave = t >> 6;      // 0..7
  const int wm   = wave >> 2;   // 0..1 -> 128-row half
  const int wn   = wave & 3;    // 0..3 -> 48-col strip
  const int quad = lane >> 4;
  const int l16  = lane & 15;

  __shared__ alignas(16) bf16 As[2][256 * 64];  // 2 x 32 KiB
  __shared__ alignas(16) bf16 Bs[2][192 * 64];  // 2 x 24 KiB  (112 KiB)

  // staging: thread t -> linear LDS slot (row = srt within 64-row unit,
  // chunk = t&7); global source pre-swizzled: chunk ^= row&7.
  const int srt = t >> 3;
  const int sct = ((t & 7) ^ (srt & 7)) << 3;
  const uint64_t abase = (uint64_t)(m0 + srt) * 1024 + sct;
  const uint64_t bbase = (uint64_t)(n0 + srt) * 1024 + sct;
  const int ldst = t * 16;

  const int pcb0 = ((quad) ^ (l16 & 7)) << 4;
  const int pcb1 = ((4 + quad) ^ (l16 & 7)) << 4;

  floatx4 acc[8][3];
#pragma unroll
  for (int i = 0; i < 8; ++i)
#pragma unroll
    for (int j = 0; j < 3; ++j) {
      floatx4 z = {0.f, 0.f, 0.f, 0.f};
      acc[i][j] = z;
    }
  bf16x8 af[2][2], bfr[3][2];

  // prologue: t0 full (B0,B1,B2,A0,A1,A2,A3); t1 partial (B0,B1,B2,A0,A2).
  SBU(0, 0, 0); SBU(0, 1, 0); SBU(0, 2, 0);
  SAU(0, 0, 0); SAU(0, 1, 0); SAU(0, 2, 0); SAU(0, 3, 0);
  SBU(1, 0, 1); SBU(1, 1, 1); SBU(1, 2, 1);
  SAU(1, 0, 1); SAU(1, 2, 1);
  asm volatile("s_waitcnt vmcnt(5)" ::: "memory");  // t0 fully arrived
  BAR();

  for (int i = 0; i < 8; ++i) {
    const int kt1 = 2 * i + 1;
    const int kt2 = 2 * i + 2;
    const int kt3 = 2 * i + 3;
    const bool pf = (i < 7);

    // p1: read buf0 mb0 + B; stage t_odd A u1,u3 (free since prev p8)
    RDA2(0, 0); RDB3(0);
    SAU(1, 1, kt1); SAU(1, 3, kt1);
    BAR(); WAITL0();
    __builtin_amdgcn_s_setprio(1); MMQ12(0); __builtin_amdgcn_s_setprio(0);
    BAR();

    // p2: read mb2; stage t2.B u0,u1 (buf0.B free after p1)
    RDA2(0, 2);
    if (pf) { SBU(0, 0, kt2); SBU(0, 1, kt2); }
    BAR(); WAITL0();
    __builtin_amdgcn_s_setprio(1); MMQ12(2); __builtin_amdgcn_s_setprio(0);
    BAR();

    // p3: read mb4; stage t2.B u2 + t2.A u0,u2 (A u0,u2 free after p2)
    RDA2(0, 4);
    if (pf) { SBU(0, 2, kt2); SAU(0, 0, kt2); SAU(0, 2, kt2); }
    BAR(); WAITL0();
    __builtin_amdgcn_s_setprio(1); MMQ12(4); __builtin_amdgcn_s_setprio(0);
    BAR();

    // p4: read mb6; wait t1 complete (5 younger loads outstanding)
    RDA2(0, 6);
    BAR(); WAITL0();
    __builtin_amdgcn_s_setprio(1); MMQ12(6); __builtin_amdgcn_s_setprio(0);
    if (pf) { asm volatile("s_waitcnt vmcnt(5)" ::: "memory"); }
    else    { asm volatile("s_waitcnt vmcnt(0)" ::: "memory"); }
    BAR();

    // p5: read buf1 mb0 + B; stage t2.A u1,u3 (free after p4)
    RDA2(1, 0); RDB3(1);
    if (pf) { SAU(0, 1, kt2); SAU(0, 3, kt2); }
    BAR(); WAITL0();
    __builtin_amdgcn_s_setprio(1); MMQ12(0); __builtin_amdgcn_s_setprio(0);
    BAR();

    // p6: read mb2; stage t3.B u0,u1 (buf1.B free after p5)
    RDA2(1, 2);
    if (pf) { SBU(1, 0, kt3); SBU(1, 1, kt3); }
    BAR(); WAITL0();
    __builtin_amdgcn_s_setprio(1); MMQ12(2); __builtin_amdgcn_s_setprio(0);
    BAR();

    // p7: read mb4; stage t3.B u2 + t3.A u0,u2 (free after p6)
    RDA2(1, 4);
    if (pf) { SBU(1, 2, kt3); SAU(1, 0, kt3); SAU(1, 2, kt3); }
    BAR(); WAITL0();
    __builtin_amdgcn_s_setprio(1); MMQ12(4); __builtin_amdgcn_s_setprio(0);
    BAR();

    // p8: read mb6; wait t2 complete (5 younger loads outstanding)
    RDA2(1, 6);
    BAR(); WAITL0();
    __builtin_amdgcn_s_setprio(1); MMQ12(6); __builtin_amdgcn_s_setprio(0);
    if (pf) { asm volatile("s_waitcnt vmcnt(5)" ::: "memory"); }
    BAR();
  }

  // epilogue: bias + f16, coalesced via LDS restage (reuse As; all LDS reads
  // of the K-loop completed before the final p8 barrier).
  float bvs[3];
#pragma unroll
  for (int nj = 0; nj < 3; ++nj) {
    const int n = n0 + wn * 48 + nj * 16 + l16;
    const int which = n >> 10;
    const int c = n & 1023;
    bvs[nj] = ((which == 0) ? b0 : (which == 1) ? b1 : b2)[c];
  }
  _Float16* stg = (_Float16*)(&As[0][0]);  // 32 rows x stride 200 halves
#pragma unroll
  for (int mi = 0; mi < 8; ++mi) {
#pragma unroll
    for (int nj = 0; nj < 3; ++nj)
#pragma unroll
      for (int r = 0; r < 4; ++r)
        stg[(wm * 16 + quad * 4 + r) * 200 + wn * 48 + nj * 16 + l16] =
            (_Float16)(acc[mi][nj][r] + bvs[nj]);
    BAR();
#pragma unroll
    for (int rep = 0; rep < 2; ++rep) {
      const int cc = t + rep * 512;
      if (cc < 768) {
        const int rl = cc / 24;
        const int ch = cc - rl * 24;
        const int mrow = m0 + (rl >> 4) * 128 + mi * 16 + (rl & 15);
        const f16x8 v = *(const f16x8*)(stg + rl * 200 + ch * 8);
        *(f16x8*)((_Float16*)qkv + (size_t)mrow * 3072 + n0 + ch * 8) = v;
      }
    }
    BAR();
  }
}

// ---------------------------------------------------------------------------
// Projection GEMM — 128x128 m97 structure. A row-major (8192,1024) bf16
// (attn output); Bt = Wo^T; out fp32 + bias.
// ---------------------------------------------------------------------------
__global__ __launch_bounds__(256) void gemm_proj(
    const bf16* __restrict__ A, const bf16* __restrict__ Bt,
    const float* __restrict__ bias, float* __restrict__ fout) {
  const int tid  = threadIdx.x;
  const int m0   = blockIdx.x * 128;
  const int n0   = blockIdx.y * 128;
  const int lane = tid & 63;
  const int wave = tid >> 6;
  const int wr   = (wave >> 1) * 64;
  const int wc   = (wave & 1) * 64;
  const int quad = lane >> 4;
  const int l16  = lane & 15;

  __shared__ alignas(16) bf16 As[128 * 64];
  __shared__ alignas(16) bf16 Bs[128 * 64];

  const int srow = tid >> 3;
  const int cg   = (tid & 7) ^ (srow & 7);
  const uint64_t aoff = (uint64_t)(m0 + srow) * 1024 + cg * 8;
  const uint64_t boff = (uint64_t)(n0 + srow) * 1024 + cg * 8;

  floatx4 acc[4][4];
#pragma unroll
  for (int i = 0; i < 4; ++i)
#pragma unroll
    for (int j = 0; j < 4; ++j) {
      floatx4 z = {0.f, 0.f, 0.f, 0.f};
      acc[i][j] = z;
    }

  for (int k0 = 0; k0 < 1024; k0 += 64) {
    __syncthreads();
#pragma unroll
    for (int it = 0; it < 4; ++it) {
      GLD_LDS16(A + aoff + (uint64_t)it * 32768 + k0, (char*)As + it * 4096 + tid * 16);
      GLD_LDS16(Bt + boff + (uint64_t)it * 32768 + k0, (char*)Bs + it * 4096 + tid * 16);
    }
    __syncthreads();

#pragma unroll
    for (int kc = 0; kc < 2; ++kc) {
      bf16x8 af[4], bfr[4];
#pragma unroll
      for (int i = 0; i < 4; ++i) {
        const int mrow = wr + i * 16 + l16;
        const int pca  = (kc * 4 + quad) ^ (mrow & 7);
        af[i] = *(const bf16x8*)(As + mrow * 64 + pca * 8);
        const int nrow = wc + i * 16 + l16;
        const int pcb  = (kc * 4 + quad) ^ (nrow & 7);
        bfr[i] = *(const bf16x8*)(Bs + nrow * 64 + pcb * 8);
      }
#pragma unroll
      for (int i = 0; i < 4; ++i)
#pragma unroll
        for (int j = 0; j < 4; ++j)
          acc[i][j] = __builtin_amdgcn_mfma_f32_16x16x32_bf16(af[i], bfr[j], acc[i][j], 0, 0, 0);
    }
  }

#pragma unroll
  for (int i = 0; i < 4; ++i)
#pragma unroll
    for (int j = 0; j < 4; ++j)
#pragma unroll
      for (int r = 0; r < 4; ++r) {
        const int m = m0 + wr + i * 16 + quad * 4 + r;
        const int n = n0 + wc + j * 16 + l16;
        fout[(uint64_t)m * 1024 + n] = acc[i][j][r] + bias[n];
      }
}

// ---------------------------------------------------------------------------
// Dilated attention — MFMA. Reads Q/K/V from row-major qkv (B,N,3072) f16;
// writes attn output row-major (B,N,1024) bf16.
// ---------------------------------------------------------------------------
#define RMAXA 32
#define VTS 176       // VT col stride (halves)
#define PS  104       // P row stride (halves)

__global__ __launch_bounds__(256) void dilated_attn_mfma_kernel(
    const __half* __restrict__ qkv, bf16* __restrict__ attn_out,
    const int* __restrict__ kptr, const int* __restrict__ dptr) {
  const int tid  = threadIdx.x;
  const int wave = tid >> 6, lane = tid & 63;
  const int quad = lane >> 4, l16 = lane & 15;
  const int bh = blockIdx.x >> 5;       // 32 query-blocks of 64 per (b,h)
  const int Q0 = (blockIdx.x & 31) * 64;
  const int b  = bh >> 4, h = bh & 15;
  const int kk  = kptr[0];
  const int dil = dptr[0];
  const int R   = kk * dil;
  const size_t xb = (size_t)b * 2048;
  const int qo = h * 64, ko = 1024 + h * 64, vo = 2048 + h * 64;
  const _Float16* Xh = (const _Float16*)qkv;

  __shared__ alignas(16) _Float16 smem[64 * VTS + 4 * 16 * PS];  // 35840 B
  _Float16* VT = smem;
  _Float16* Pw = smem + 64 * VTS + wave * 16 * PS;

  const bool fast = (R <= RMAXA) && (dil >= 1);

  if (fast) {
    // zero-fill VT + P (guards / pad cols must be 0, not stale/NaN bits)
    {
      const int nch = (64 * VTS + 4 * 16 * PS) / 8;
      const f16x8 z = {0, 0, 0, 0, 0, 0, 0, 0};
      for (int c = tid; c < nch; c += 256) ((f16x8*)smem)[c] = z;
    }
    __syncthreads();

    // stage V transposed: VT[dh][col], col = j - (Q0-R) + 32
    const int jlo = Q0 - R;  // unclamped
    const int lo = (jlo > 0) ? jlo : 0;
    const int hi = (Q0 + 63 + R < 2047) ? Q0 + 63 + R : 2047;
    const int nrows = hi - lo + 1;
    for (int idx = tid; idx < nrows * 8; idx += 256) {
      const int r = idx >> 3, c = idx & 7;
      const int j = lo + r;
      const f16x8 v = *(const f16x8*)(Xh + (xb + j) * 3072 + vo + c * 8);
      const int col = j - jlo + 32;
#pragma unroll
      for (int s = 0; s < 8; ++s) VT[(c * 8 + s) * VTS + col] = v[s];
    }
    __syncthreads();

    const int i0 = Q0 + wave * 16;
    // Q A-frags (2 k-chunks of 32 over DH=64)
    const f16x8 a0 = *(const f16x8*)(Xh + (xb + i0 + l16) * 3072 + qo + quad * 8);
    const f16x8 a1 = *(const f16x8*)(Xh + (xb + i0 + l16) * 3072 + qo + 32 + quad * 8);

    const int nkt = (16 + 2 * R + 15) >> 4;   // key tiles of 16
    const int jw0 = i0 - R;                   // wave key-window start
    float lsum[4] = {0.f, 0.f, 0.f, 0.f};
    const floatx4 zf = {0.f, 0.f, 0.f, 0.f};

    for (int kt = 0; kt < nkt; ++kt) {
      const int j0 = jw0 + 16 * kt;
      const int jn = j0 + l16;                        // this lane's key
      const int jc = (jn < 0) ? 0 : (jn > 2047 ? 2047 : jn);
      const f16x8 k0v = *(const f16x8*)(Xh + (xb + jc) * 3072 + ko + quad * 8);
      const f16x8 k1v = *(const f16x8*)(Xh + (xb + jc) * 3072 + ko + 32 + quad * 8);
      floatx4 s4 = __builtin_amdgcn_mfma_f32_16x16x32_f16(a0, k0v, zf, 0, 0, 0);
      s4 = __builtin_amdgcn_mfma_f32_16x16x32_f16(a1, k1v, s4, 0, 0, 0);
#pragma unroll
      for (int r = 0; r < 4; ++r) {
        const int m = quad * 4 + r;
        const int d = jn - (i0 + m);
        const bool valid = ((unsigned)jn < 2048u) && (d >= -R) && (d <= R) && (d % dil == 0);
        const float pe = valid ? __expf(s4[r] * 0.125f) : 0.f;
        lsum[r] += pe;
        Pw[m * PS + kt * 16 + l16] = (_Float16)pe;
      }
    }
    // row sums: reduce across the 16 lanes of each quad
#pragma unroll
    for (int r = 0; r < 4; ++r) {
      lsum[r] += __shfl_xor(lsum[r], 1);
      lsum[r] += __shfl_xor(lsum[r], 2);
      lsum[r] += __shfl_xor(lsum[r], 4);
      lsum[r] += __shfl_xor(lsum[r], 8);
    }

    // PV: o[t](16 x 16dh) accumulated f32; A = P[m=lane&15][k], B = VT
    const int nkc = (nkt * 16 + 31) >> 5;     // 32-wide k-chunks
    floatx4 o[4] = {zf, zf, zf, zf};
    const int vbase = 16 * wave + 32;         // VT col of k_rel = 0
    for (int c = 0; c < nkc; ++c) {
      const f16x8 pa = *(const f16x8*)(Pw + l16 * PS + c * 32 + quad * 8);
#pragma unroll
      for (int t = 0; t < 4; ++t) {
        const f16x8 vb = *(const f16x8*)(VT + (t * 16 + l16) * VTS + vbase + c * 32 + quad * 8);
        o[t] = __builtin_amdgcn_mfma_f32_16x16x32_f16(pa, vb, o[t], 0, 0, 0);
      }
    }

    // normalize + stage O into Pw ([m][dh], stride PS), then coalesced store
#pragma unroll
    for (int t = 0; t < 4; ++t) {
#pragma unroll
      for (int r = 0; r < 4; ++r)
        Pw[(quad * 4 + r) * PS + t * 16 + l16] = (_Float16)(o[t][r] / lsum[r]);
    }
    const int orow = lane >> 2, oseg = lane & 3;
#pragma unroll
    for (int hseg = 0; hseg < 2; ++hseg) {
      const f16x8 ov = *(const f16x8*)(Pw + orow * PS + oseg * 16 + hseg * 8);
      bf16 ob[8];
#pragma unroll
      for (int s = 0; s < 8; ++s) ob[s] = (bf16)(float)ov[s];
      *(uint4*)(attn_out + (xb + i0 + orow) * 1024 + h * 64 + oseg * 16 + hseg * 8) =
          *(const uint4*)ob;
    }
    return;
  }

  // ---- fallback: rarely taken; plain per-lane scalar loop ----
  if (tid < 64) {
    const int i = Q0 + tid;
    float l = 0.f;
    float oacc[64];
#pragma unroll
    for (int u = 0; u < 64; ++u) oacc[u] = 0.f;
    float qv[64];
#pragma unroll
    for (int u = 0; u < 64; ++u) qv[u] = (float)Xh[(xb + i) * 3072 + qo + u];
    for (int tt = -kk; tt <= kk; ++tt) {
      const int j = i + (int)((long long)tt * dil);
      if (j < 0 || j >= 2048) continue;
      float s = 0.f;
      for (int u = 0; u < 64; ++u) s += qv[u] * (float)Xh[(xb + j) * 3072 + ko + u];
      const float pe = __expf(s * 0.125f);
      l += pe;
      for (int u = 0; u < 64; ++u) oacc[u] += pe * (float)Xh[(xb + j) * 3072 + vo + u];
    }
    for (int u = 0; u < 64; ++u)
      attn_out[(xb + i) * 1024 + h * 64 + u] = (bf16)(oacc[u] / l);
  }
}

// ---------------------------------------------------------------------------
extern "C" void kernel_launch(void* const* d_in, const int* in_sizes, int n_in,
                              void* d_out, int out_size, void* d_ws, size_t ws_size,
                              hipStream_t stream) {
  const float* x  = (const float*)d_in[0];
  const float* Wq = (const float*)d_in[1];
  const float* bq = (const float*)d_in[2];
  const float* Wk = (const float*)d_in[3];
  const float* bk = (const float*)d_in[4];
  const float* Wv = (const float*)d_in[5];
  const float* bv = (const float*)d_in[6];
  const float* Wo = (const float*)d_in[7];
  const float* bo = (const float*)d_in[8];
  const int* kp   = (const int*)d_in[9];
  const int* dp   = (const int*)d_in[10];
  float* out = (float*)d_out;

  bf16*   xbf   = (bf16*)d_ws;                   // 8388608  (B,N,D) bf16
  bf16*   WTqkv = xbf + 8388608;                 // 3072*1024 bf16
  bf16*   WoT   = WTqkv + 3072 * 1024;           // 1024*1024 bf16
  __half* qkv   = (__half*)(WoT + 1024 * 1024);  // 8192*3072 f16 row-major
  bf16*   attnO = xbf;                           // alias: (B,N,1024) bf16

  prep_kernel<<<dim3(3072), 256, 0, stream>>>(x, Wq, Wk, Wv, Wo, xbf, WTqkv, WoT);

  gemm_qkv_8ph<<<dim3(32, 16), 512, 0, stream>>>(xbf, WTqkv, bq, bk, bv, qkv);

  dilated_attn_mfma_kernel<<<dim3(2048), 256, 0, stream>>>(qkv, attnO, kp, dp);

  gemm_proj<<<dim3(64, 8), 256, 0, stream>>>(attnO, WoT, bo, out);
}

// Round 7
// 206.426 us; speedup vs baseline: 1.0401x; 1.0088x over previous
//
#include <hip/hip_runtime.h>
#include <hip/hip_bf16.h>
#include <hip/hip_fp16.h>
#include <stdint.h>

using bf16 = __hip_bfloat16;

typedef __bf16    bf16x8 __attribute__((ext_vector_type(8)));
typedef float     floatx4 __attribute__((ext_vector_type(4)));
typedef _Float16  f16x8 __attribute__((ext_vector_type(8)));

typedef __attribute__((address_space(3))) void as3_void;
typedef __attribute__((address_space(1))) void as1_void;

// async global->LDS, 16B/lane; LDS dest is wave-uniform base + lane*16.
#define GLD_LDS16(gp, lp) \
  __builtin_amdgcn_global_load_lds((as1_void*)(uintptr_t)(gp), (as3_void*)(uintptr_t)(lp), 16, 0, 0)

#define FENCE() asm volatile("" ::: "memory")
#define BAR()   do { FENCE(); __builtin_amdgcn_s_barrier(); FENCE(); } while (0)
#define WAITL0() do { asm volatile("s_waitcnt lgkmcnt(0)" ::: "memory"); \
                      __builtin_amdgcn_sched_barrier(0); } while (0)

// ---------------------------------------------------------------------------
// prep: blocks 0..1023 transpose W (fp32 [k][n] -> bf16 [n][k]); blocks
// 1024..3071 convert x fp32->bf16 (32 B stores/thread).
// ---------------------------------------------------------------------------
__global__ __launch_bounds__(256) void prep_kernel(
    const float* __restrict__ x,
    const float* __restrict__ Wq, const float* __restrict__ Wk,
    const float* __restrict__ Wv, const float* __restrict__ Wo,
    bf16* __restrict__ xbf, bf16* __restrict__ WTqkv, bf16* __restrict__ WoT) {
  __shared__ float tile[64 * 68];
  const int blk = blockIdx.x;
  const int tid = threadIdx.x;
  if (blk < 1024) {
    const int z = blk >> 8, t = blk & 255;
    const float* src = (z == 0) ? Wq : (z == 1) ? Wk : (z == 2) ? Wv : Wo;
    bf16* dst = (z < 3) ? (WTqkv + (size_t)z * 1024 * 1024) : WoT;
    const int nbase = (t & 15) * 64, kbase = (t >> 4) * 64;
    const int r1 = tid >> 4, c1 = tid & 15;
#pragma unroll
    for (int it = 0; it < 4; ++it) {
      const int row = r1 + it * 16;
      const float4 v = *(const float4*)(src + (size_t)(kbase + row) * 1024 + nbase + c1 * 4);
      *(float4*)(tile + row * 68 + c1 * 4) = v;
    }
    __syncthreads();
    const int c2 = tid & 7, n2 = tid >> 3;
#pragma unroll
    for (int it2 = 0; it2 < 2; ++it2) {
      const int n = n2 + it2 * 32;
      bf16 o[8];
#pragma unroll
      for (int s = 0; s < 8; ++s) o[s] = (bf16)tile[(8 * c2 + s) * 68 + n];
      *(uint4*)(dst + (size_t)(nbase + n) * 1024 + kbase + 8 * c2) = *(const uint4*)o;
    }
  } else {
    const size_t basei = ((size_t)(blk - 1024) * 256 + tid) * 16;
#pragma unroll
    for (int h = 0; h < 2; ++h) {
      const float4 a = *(const float4*)(x + basei + h * 8);
      const float4 b = *(const float4*)(x + basei + h * 8 + 4);
      bf16 o[8] = {(bf16)a.x, (bf16)a.y, (bf16)a.z, (bf16)a.w,
                   (bf16)b.x, (bf16)b.y, (bf16)b.z, (bf16)b.w};
      *(uint4*)(xbf + basei + h * 8) = *(const uint4*)o;
    }
  }
}

// ---------------------------------------------------------------------------
// QKV GEMM — BM=256 x BN=192, BK=64, grid 32x16 = 512 blocks = exact 2 rounds.
// R7 restructure (from R6 cycle model: LDS-read pipe 2112 cyc/K-tile vs MFMA
// 1862 was co-critical, 16 barriers/iter):
//  - wave split 4x2 (per-wave 64x96): 20 ds_read_b128/wave/K-tile (was 22);
//    B-frags (48 VGPR) read once per K-tile, live across both phases.
//  - 2 phases per K-tile, 24 MFMA each: barriers/iter 16 -> 8.
//  - stage slots never touch a region read in the same phase:
//      A1: buf1.A0-3(t1) | A2: buf0.B0-2(t2) | B1: buf0.A0-3(t2) | B2: buf1.B0-2(t3)
//    drains: end of A2/B2, 10 outstanding, next tile = oldest 7 -> vmcnt(3).
//  - single-pass epilogue: stage all acc to LDS (256x200 f16 = 100KB over the
//    whole smem), 1 barrier, 12 vectorized f16x8 stores/thread.
// ---------------------------------------------------------------------------
#define SAU(bufi, u, kt) \
  GLD_LDS16(A + abase + (uint64_t)(u) * 65536 + (uint64_t)(kt) * 64, \
            (char*)Asp[bufi] + (u) * 8192 + ldst)
#define SBU(bufi, u, kt) \
  GLD_LDS16(Bt + bbase + (uint64_t)(u) * 65536 + (uint64_t)(kt) * 64, \
            (char*)Bsp[bufi] + (u) * 8192 + ldst)

#define RDA2(bufi, mb) do { \
    const char* _p = (const char*)Asp[bufi] + (wm * 64 + (mb) * 16 + l16) * 128; \
    af[0][0] = *(const bf16x8*)(_p + pcb0); \
    af[0][1] = *(const bf16x8*)(_p + pcb1); \
    af[1][0] = *(const bf16x8*)(_p + 2048 + pcb0); \
    af[1][1] = *(const bf16x8*)(_p + 2048 + pcb1); \
  } while (0)

#define RDB6(bufi) do { \
    const char* _p = (const char*)Bsp[bufi] + (wn * 96 + l16) * 128; \
    _Pragma("unroll") for (int _j = 0; _j < 6; ++_j) { \
      bfr[_j][0] = *(const bf16x8*)(_p + _j * 2048 + pcb0); \
      bfr[_j][1] = *(const bf16x8*)(_p + _j * 2048 + pcb1); \
    } \
  } while (0)

#define MMQ24(mb) do { \
    _Pragma("unroll") for (int _i = 0; _i < 2; ++_i) \
      _Pragma("unroll") for (int _j = 0; _j < 6; ++_j) \
        _Pragma("unroll") for (int _k = 0; _k < 2; ++_k) \
          acc[(mb) + _i][_j] = __builtin_amdgcn_mfma_f32_16x16x32_bf16( \
              af[_i][_k], bfr[_j][_k], acc[(mb) + _i][_j], 0, 0, 0); \
  } while (0)

__global__ __launch_bounds__(512, 2) void gemm_qkv_8ph(
    const bf16* __restrict__ A, const bf16* __restrict__ Bt,
    const float* __restrict__ b0, const float* __restrict__ b1, const float* __restrict__ b2,
    __half* __restrict__ qkv) {
  const int t    = threadIdx.x;
  const int m0   = blockIdx.x * 256;
  const int n0   = blockIdx.y * 192;
  const int lane = t & 63;
  const int wave = t >> 6;      // 0..7
  const int wm   = wave >> 1;   // 0..3 -> 64-row strip
  const int wn   = wave & 1;    // 0..1 -> 96-col strip
  const int quad = lane >> 4;
  const int l16  = lane & 15;

  // A dbuf 2x32KB @0, B dbuf 2x24KB @65536; epilogue reuses all 112KB.
  __shared__ alignas(16) char smem[114688];
  bf16* const Asp[2] = {(bf16*)smem, (bf16*)(smem + 32768)};
  bf16* const Bsp[2] = {(bf16*)(smem + 65536), (bf16*)(smem + 90112)};

  // staging: thread t -> linear LDS slot (row = srt within 64-row unit,
  // chunk = t&7); global source pre-swizzled: chunk ^= row&7.
  const int srt = t >> 3;
  const int sct = ((t & 7) ^ (srt & 7)) << 3;
  const uint64_t abase = (uint64_t)(m0 + srt) * 1024 + sct;
  const uint64_t bbase = (uint64_t)(n0 + srt) * 1024 + sct;
  const int ldst = t * 16;

  const int pcb0 = ((quad) ^ (l16 & 7)) << 4;
  const int pcb1 = ((4 + quad) ^ (l16 & 7)) << 4;

  floatx4 acc[4][6];
#pragma unroll
  for (int i = 0; i < 4; ++i)
#pragma unroll
    for (int j = 0; j < 6; ++j) {
      floatx4 z = {0.f, 0.f, 0.f, 0.f};
      acc[i][j] = z;
    }
  bf16x8 af[2][2], bfr[6][2];

  // prologue: t0 full (7 units) -> buf0; t1.B (3 units) -> buf1.
  SBU(0, 0, 0); SBU(0, 1, 0); SBU(0, 2, 0);
  SAU(0, 0, 0); SAU(0, 1, 0); SAU(0, 2, 0); SAU(0, 3, 0);
  SBU(1, 0, 1); SBU(1, 1, 1); SBU(1, 2, 1);
  asm volatile("s_waitcnt vmcnt(3)" ::: "memory");  // t0's 7 arrived
  BAR();

  for (int i = 0; i < 8; ++i) {
    const int kt1 = 2 * i + 1;
    const int kt2 = 2 * i + 2;
    const int kt3 = 2 * i + 3;
    const bool pf = (i < 7);

    // A1: read buf0 A[mb0-1]+B(all); stage buf1.A0-3 (t1; free since prev B2)
    RDA2(0, 0); RDB6(0);
    SAU(1, 0, kt1); SAU(1, 1, kt1); SAU(1, 2, kt1); SAU(1, 3, kt1);
    BAR(); WAITL0();
    __builtin_amdgcn_s_setprio(1); MMQ24(0); __builtin_amdgcn_s_setprio(0);
    BAR();

    // A2: read buf0 A[mb2-3]; stage buf0.B0-2 (t2; free after A1); drain t1
    RDA2(0, 2);
    if (pf) { SBU(0, 0, kt2); SBU(0, 1, kt2); SBU(0, 2, kt2); }
    BAR(); WAITL0();
    __builtin_amdgcn_s_setprio(1); MMQ24(2); __builtin_amdgcn_s_setprio(0);
    if (pf) { asm volatile("s_waitcnt vmcnt(3)" ::: "memory"); }
    else    { asm volatile("s_waitcnt vmcnt(0)" ::: "memory"); }
    BAR();

    // B1: read buf1 A[mb0-1]+B(all); stage buf0.A0-3 (t2; free after A2)
    RDA2(1, 0); RDB6(1);
    if (pf) { SAU(0, 0, kt2); SAU(0, 1, kt2); SAU(0, 2, kt2); SAU(0, 3, kt2); }
    BAR(); WAITL0();
    __builtin_amdgcn_s_setprio(1); MMQ24(0); __builtin_amdgcn_s_setprio(0);
    BAR();

    // B2: read buf1 A[mb2-3]; stage buf1.B0-2 (t3; free after B1); drain t2
    RDA2(1, 2);
    if (pf) { SBU(1, 0, kt3); SBU(1, 1, kt3); SBU(1, 2, kt3); }
    BAR(); WAITL0();
    __builtin_amdgcn_s_setprio(1); MMQ24(2); __builtin_amdgcn_s_setprio(0);
    if (pf) { asm volatile("s_waitcnt vmcnt(3)" ::: "memory"); }
    BAR();
  }

  // epilogue: bias + f16; single LDS restage (256 rows x stride 200 halves =
  // 100KB over smem), one barrier, then 12 coalesced f16x8 stores per thread.
  float bvs[6];
#pragma unroll
  for (int nj = 0; nj < 6; ++nj) {
    const int n = n0 + wn * 96 + nj * 16 + l16;
    const int which = n >> 10;
    const int c = n & 1023;
    bvs[nj] = ((which == 0) ? b0 : (which == 1) ? b1 : b2)[c];
  }
  _Float16* stg = (_Float16*)smem;
#pragma unroll
  for (int mb = 0; mb < 4; ++mb)
#pragma unroll
    for (int nj = 0; nj < 6; ++nj)
#pragma unroll
      for (int r = 0; r < 4; ++r)
        stg[(wm * 64 + mb * 16 + quad * 4 + r) * 200 + wn * 96 + nj * 16 + l16] =
            (_Float16)(acc[mb][nj][r] + bvs[nj]);
  BAR();
#pragma unroll
  for (int rep = 0; rep < 12; ++rep) {
    const int cc = t + rep * 512;     // 0..6143 = 256 rows x 24 chunks
    const int rl = cc / 24;
    const int ch = cc - rl * 24;
    const f16x8 v = *(const f16x8*)(stg + rl * 200 + ch * 8);
    *(f16x8*)((_Float16*)qkv + (size_t)(m0 + rl) * 3072 + n0 + ch * 8) = v;
  }
}

// ---------------------------------------------------------------------------
// Projection GEMM — 128x128 m97 structure. A row-major (8192,1024) bf16
// (attn output); Bt = Wo^T; out fp32 + bias.
// ---------------------------------------------------------------------------
__global__ __launch_bounds__(256) void gemm_proj(
    const bf16* __restrict__ A, const bf16* __restrict__ Bt,
    const float* __restrict__ bias, float* __restrict__ fout) {
  const int tid  = threadIdx.x;
  const int m0   = blockIdx.x * 128;
  const int n0   = blockIdx.y * 128;
  const int lane = tid & 63;
  const int wave = tid >> 6;
  const int wr   = (wave >> 1) * 64;
  const int wc   = (wave & 1) * 64;
  const int quad = lane >> 4;
  const int l16  = lane & 15;

  __shared__ alignas(16) bf16 As[128 * 64];
  __shared__ alignas(16) bf16 Bs[128 * 64];

  const int srow = tid >> 3;
  const int cg   = (tid & 7) ^ (srow & 7);
  const uint64_t aoff = (uint64_t)(m0 + srow) * 1024 + cg * 8;
  const uint64_t boff = (uint64_t)(n0 + srow) * 1024 + cg * 8;

  floatx4 acc[4][4];
#pragma unroll
  for (int i = 0; i < 4; ++i)
#pragma unroll
    for (int j = 0; j < 4; ++j) {
      floatx4 z = {0.f, 0.f, 0.f, 0.f};
      acc[i][j] = z;
    }

  for (int k0 = 0; k0 < 1024; k0 += 64) {
    __syncthreads();
#pragma unroll
    for (int it = 0; it < 4; ++it) {
      GLD_LDS16(A + aoff + (uint64_t)it * 32768 + k0, (char*)As + it * 4096 + tid * 16);
      GLD_LDS16(Bt + boff + (uint64_t)it * 32768 + k0, (char*)Bs + it * 4096 + tid * 16);
    }
    __syncthreads();

#pragma unroll
    for (int kc = 0; kc < 2; ++kc) {
      bf16x8 af[4], bfr[4];
#pragma unroll
      for (int i = 0; i < 4; ++i) {
        const int mrow = wr + i * 16 + l16;
        const int pca  = (kc * 4 + quad) ^ (mrow & 7);
        af[i] = *(const bf16x8*)(As + mrow * 64 + pca * 8);
        const int nrow = wc + i * 16 + l16;
        const int pcb  = (kc * 4 + quad) ^ (nrow & 7);
        bfr[i] = *(const bf16x8*)(Bs + nrow * 64 + pcb * 8);
      }
#pragma unroll
      for (int i = 0; i < 4; ++i)
#pragma unroll
        for (int j = 0; j < 4; ++j)
          acc[i][j] = __builtin_amdgcn_mfma_f32_16x16x32_bf16(af[i], bfr[j], acc[i][j], 0, 0, 0);
    }
  }

#pragma unroll
  for (int i = 0; i < 4; ++i)
#pragma unroll
    for (int j = 0; j < 4; ++j)
#pragma unroll
      for (int r = 0; r < 4; ++r) {
        const int m = m0 + wr + i * 16 + quad * 4 + r;
        const int n = n0 + wc + j * 16 + l16;
        fout[(uint64_t)m * 1024 + n] = acc[i][j][r] + bias[n];
      }
}

// ---------------------------------------------------------------------------
// Dilated attention — MFMA. Reads Q/K/V from row-major qkv (B,N,3072) f16;
// writes attn output row-major (B,N,1024) bf16.
// ---------------------------------------------------------------------------
#define RMAXA 32
#define VTS 176       // VT col stride (halves)
#define PS  104       // P row stride (halves)

__global__ __launch_bounds__(256) void dilated_attn_mfma_kernel(
    const __half* __restrict__ qkv, bf16* __restrict__ attn_out,
    const int* __restrict__ kptr, const int* __restrict__ dptr) {
  const int tid  = threadIdx.x;
  const int wave = tid >> 6, lane = tid & 63;
  const int quad = lane >> 4, l16 = lane & 15;
  const int bh = blockIdx.x >> 5;       // 32 query-blocks of 64 per (b,h)
  const int Q0 = (blockIdx.x & 31) * 64;
  const int b  = bh >> 4, h = bh & 15;
  const int kk  = kptr[0];
  const int dil = dptr[0];
  const int R   = kk * dil;
  const size_t xb = (size_t)b * 2048;
  const int qo = h * 64, ko = 1024 + h * 64, vo = 2048 + h * 64;
  const _Float16* Xh = (const _Float16*)qkv;

  __shared__ alignas(16) _Float16 smem[64 * VTS + 4 * 16 * PS];  // 35840 B
  _Float16* VT = smem;
  _Float16* Pw = smem + 64 * VTS + wave * 16 * PS;

  const bool fast = (R <= RMAXA) && (dil >= 1);

  if (fast) {
    // zero-fill VT + P (guards / pad cols must be 0, not stale/NaN bits)
    {
      const int nch = (64 * VTS + 4 * 16 * PS) / 8;
      const f16x8 z = {0, 0, 0, 0, 0, 0, 0, 0};
      for (int c = tid; c < nch; c += 256) ((f16x8*)smem)[c] = z;
    }
    __syncthreads();

    // stage V transposed: VT[dh][col], col = j - (Q0-R) + 32
    const int jlo = Q0 - R;  // unclamped
    const int lo = (jlo > 0) ? jlo : 0;
    const int hi = (Q0 + 63 + R < 2047) ? Q0 + 63 + R : 2047;
    const int nrows = hi - lo + 1;
    for (int idx = tid; idx < nrows * 8; idx += 256) {
      const int r = idx >> 3, c = idx & 7;
      const int j = lo + r;
      const f16x8 v = *(const f16x8*)(Xh + (xb + j) * 3072 + vo + c * 8);
      const int col = j - jlo + 32;
#pragma unroll
      for (int s = 0; s < 8; ++s) VT[(c * 8 + s) * VTS + col] = v[s];
    }
    __syncthreads();

    const int i0 = Q0 + wave * 16;
    // Q A-frags (2 k-chunks of 32 over DH=64)
    const f16x8 a0 = *(const f16x8*)(Xh + (xb + i0 + l16) * 3072 + qo + quad * 8);
    const f16x8 a1 = *(const f16x8*)(Xh + (xb + i0 + l16) * 3072 + qo + 32 + quad * 8);

    const int nkt = (16 + 2 * R + 15) >> 4;   // key tiles of 16
    const int jw0 = i0 - R;                   // wave key-window start
    float lsum[4] = {0.f, 0.f, 0.f, 0.f};
    const floatx4 zf = {0.f, 0.f, 0.f, 0.f};

    for (int kt = 0; kt < nkt; ++kt) {
      const int j0 = jw0 + 16 * kt;
      const int jn = j0 + l16;                        // this lane's key
      const int jc = (jn < 0) ? 0 : (jn > 2047 ? 2047 : jn);
      const f16x8 k0v = *(const f16x8*)(Xh + (xb + jc) * 3072 + ko + quad * 8);
      const f16x8 k1v = *(const f16x8*)(Xh + (xb + jc) * 3072 + ko + 32 + quad * 8);
      floatx4 s4 = __builtin_amdgcn_mfma_f32_16x16x32_f16(a0, k0v, zf, 0, 0, 0);
      s4 = __builtin_amdgcn_mfma_f32_16x16x32_f16(a1, k1v, s4, 0, 0, 0);
#pragma unroll
      for (int r = 0; r < 4; ++r) {
        const int m = quad * 4 + r;
        const int d = jn - (i0 + m);
        const bool valid = ((unsigned)jn < 2048u) && (d >= -R) && (d <= R) && (d % dil == 0);
        const float pe = valid ? __expf(s4[r] * 0.125f) : 0.f;
        lsum[r] += pe;
        Pw[m * PS + kt * 16 + l16] = (_Float16)pe;
      }
    }
    // row sums: reduce across the 16 lanes of each quad
#pragma unroll
    for (int r = 0; r < 4; ++r) {
      lsum[r] += __shfl_xor(lsum[r], 1);
      lsum[r] += __shfl_xor(lsum[r], 2);
      lsum[r] += __shfl_xor(lsum[r], 4);
      lsum[r] += __shfl_xor(lsum[r], 8);
    }

    // PV: o[t](16 x 16dh) accumulated f32; A = P[m=lane&15][k], B = VT
    const int nkc = (nkt * 16 + 31) >> 5;     // 32-wide k-chunks
    floatx4 o[4] = {zf, zf, zf, zf};
    const int vbase = 16 * wave + 32;         // VT col of k_rel = 0
    for (int c = 0; c < nkc; ++c) {
      const f16x8 pa = *(const f16x8*)(Pw + l16 * PS + c * 32 + quad * 8);
#pragma unroll
      for (int t = 0; t < 4; ++t) {
        const f16x8 vb = *(const f16x8*)(VT + (t * 16 + l16) * VTS + vbase + c * 32 + quad * 8);
        o[t] = __builtin_amdgcn_mfma_f32_16x16x32_f16(pa, vb, o[t], 0, 0, 0);
      }
    }

    // normalize + stage O into Pw ([m][dh], stride PS), then coalesced store
#pragma unroll
    for (int t = 0; t < 4; ++t) {
#pragma unroll
      for (int r = 0; r < 4; ++r)
        Pw[(quad * 4 + r) * PS + t * 16 + l16] = (_Float16)(o[t][r] / lsum[r]);
    }
    const int orow = lane >> 2, oseg = lane & 3;
#pragma unroll
    for (int hseg = 0; hseg < 2; ++hseg) {
      const f16x8 ov = *(const f16x8*)(Pw + orow * PS + oseg * 16 + hseg * 8);
      bf16 ob[8];
#pragma unroll
      for (int s = 0; s < 8; ++s) ob[s] = (bf16)(float)ov[s];
      *(uint4*)(attn_out + (xb + i0 + orow) * 1024 + h * 64 + oseg * 16 + hseg * 8) =
          *(const uint4*)ob;
    }
    return;
  }

  // ---- fallback: rarely taken; plain per-lane scalar loop ----
  if (tid < 64) {
    const int i = Q0 + tid;
    float l = 0.f;
    float oacc[64];
#pragma unroll
    for (int u = 0; u < 64; ++u) oacc[u] = 0.f;
    float qv[64];
#pragma unroll
    for (int u = 0; u < 64; ++u) qv[u] = (float)Xh[(xb + i) * 3072 + qo + u];
    for (int tt = -kk; tt <= kk; ++tt) {
      const int j = i + (int)((long long)tt * dil);
      if (j < 0 || j >= 2048) continue;
      float s = 0.f;
      for (int u = 0; u < 64; ++u) s += qv[u] * (float)Xh[(xb + j) * 3072 + ko + u];
      const float pe = __expf(s * 0.125f);
      l += pe;
      for (int u = 0; u < 64; ++u) oacc[u] += pe * (float)Xh[(xb + j) * 3072 + vo + u];
    }
    for (int u = 0; u < 64; ++u)
      attn_out[(xb + i) * 1024 + h * 64 + u] = (bf16)(oacc[u] / l);
  }
}

// ---------------------------------------------------------------------------
extern "C" void kernel_launch(void* const* d_in, const int* in_sizes, int n_in,
                              void* d_out, int out_size, void* d_ws, size_t ws_size,
                              hipStream_t stream) {
  const float* x  = (const float*)d_in[0];
  const float* Wq = (const float*)d_in[1];
  const float* bq = (const float*)d_in[2];
  const float* Wk = (const float*)d_in[3];
  const float* bk = (const float*)d_in[4];
  const float* Wv = (const float*)d_in[5];
  const float* bv = (const float*)d_in[6];
  const float* Wo = (const float*)d_in[7];
  const float* bo = (const float*)d_in[8];
  const int* kp   = (const int*)d_in[9];
  const int* dp   = (const int*)d_in[10];
  float* out = (float*)d_out;

  bf16*   xbf   = (bf16*)d_ws;                   // 8388608  (B,N,D) bf16
  bf16*   WTqkv = xbf + 8388608;                 // 3072*1024 bf16
  bf16*   WoT   = WTqkv + 3072 * 1024;           // 1024*1024 bf16
  __half* qkv   = (__half*)(WoT + 1024 * 1024);  // 8192*3072 f16 row-major
  bf16*   attnO = xbf;                           // alias: (B,N,1024) bf16

  prep_kernel<<<dim3(3072), 256, 0, stream>>>(x, Wq, Wk, Wv, Wo, xbf, WTqkv, WoT);

  gemm_qkv_8ph<<<dim3(32, 16), 512, 0, stream>>>(xbf, WTqkv, bq, bk, bv, qkv);

  dilated_attn_mfma_kernel<<<dim3(2048), 256, 0, stream>>>(qkv, attnO, kp, dp);

  gemm_proj<<<dim3(64, 8), 256, 0, stream>>>(attnO, WoT, bo, out);
}

// Round 8
// 202.718 us; speedup vs baseline: 1.0592x; 1.0183x over previous
//
#include <hip/hip_runtime.h>
#include <hip/hip_bf16.h>
#include <hip/hip_fp16.h>
#include <stdint.h>

using bf16 = __hip_bfloat16;

typedef __bf16    bf16x8 __attribute__((ext_vector_type(8)));
typedef float     floatx4 __attribute__((ext_vector_type(4)));
typedef _Float16  f16x8 __attribute__((ext_vector_type(8)));

typedef __attribute__((address_space(3))) void as3_void;
typedef __attribute__((address_space(1))) void as1_void;

// async global->LDS, 16B/lane; LDS dest is wave-uniform base + lane*16.
#define GLD_LDS16(gp, lp) \
  __builtin_amdgcn_global_load_lds((as1_void*)(uintptr_t)(gp), (as3_void*)(uintptr_t)(lp), 16, 0, 0)

#define FENCE() asm volatile("" ::: "memory")
#define BAR()   do { FENCE(); __builtin_amdgcn_s_barrier(); FENCE(); } while (0)
// pin everything (MFMAs + their compiler-inserted lgkm waits) before the
// following barrier; do NOT add lgkmcnt(0) — let the compiler interleave
// fine-grained waits with the MFMA cluster (m97 evidence: it does).
#define PIN()   __builtin_amdgcn_sched_barrier(0)

// ---------------------------------------------------------------------------
// prep: blocks 0..1023 transpose W (fp32 [k][n] -> bf16 [n][k]); blocks
// 1024..3071 convert x fp32->bf16 (32 B stores/thread).
// ---------------------------------------------------------------------------
__global__ __launch_bounds__(256) void prep_kernel(
    const float* __restrict__ x,
    const float* __restrict__ Wq, const float* __restrict__ Wk,
    const float* __restrict__ Wv, const float* __restrict__ Wo,
    bf16* __restrict__ xbf, bf16* __restrict__ WTqkv, bf16* __restrict__ WoT) {
  __shared__ float tile[64 * 68];
  const int blk = blockIdx.x;
  const int tid = threadIdx.x;
  if (blk < 1024) {
    const int z = blk >> 8, t = blk & 255;
    const float* src = (z == 0) ? Wq : (z == 1) ? Wk : (z == 2) ? Wv : Wo;
    bf16* dst = (z < 3) ? (WTqkv + (size_t)z * 1024 * 1024) : WoT;
    const int nbase = (t & 15) * 64, kbase = (t >> 4) * 64;
    const int r1 = tid >> 4, c1 = tid & 15;
#pragma unroll
    for (int it = 0; it < 4; ++it) {
      const int row = r1 + it * 16;
      const float4 v = *(const float4*)(src + (size_t)(kbase + row) * 1024 + nbase + c1 * 4);
      *(float4*)(tile + row * 68 + c1 * 4) = v;
    }
    __syncthreads();
    const int c2 = tid & 7, n2 = tid >> 3;
#pragma unroll
    for (int it2 = 0; it2 < 2; ++it2) {
      const int n = n2 + it2 * 32;
      bf16 o[8];
#pragma unroll
      for (int s = 0; s < 8; ++s) o[s] = (bf16)tile[(8 * c2 + s) * 68 + n];
      *(uint4*)(dst + (size_t)(nbase + n) * 1024 + kbase + 8 * c2) = *(const uint4*)o;
    }
  } else {
    const size_t basei = ((size_t)(blk - 1024) * 256 + tid) * 16;
#pragma unroll
    for (int h = 0; h < 2; ++h) {
      const float4 a = *(const float4*)(x + basei + h * 8);
      const float4 b = *(const float4*)(x + basei + h * 8 + 4);
      bf16 o[8] = {(bf16)a.x, (bf16)a.y, (bf16)a.z, (bf16)a.w,
                   (bf16)b.x, (bf16)b.y, (bf16)b.z, (bf16)b.w};
      *(uint4*)(xbf + basei + h * 8) = *(const uint4*)o;
    }
  }
}

// ---------------------------------------------------------------------------
// QKV GEMM — BM=256 x BN=192, BK=64, grid 32x16 = 512 blocks = exact 2 rounds.
// R8: remove the mid-phase BAR+lgkmcnt(0) that serialized the LDS-read pipe
// against the MFMA pipe (R6/R7 cycle model: sum 3912 cyc ~= measured 4275).
// Each phase is now {read-issue; stage-issue; MFMA (compiler-interleaved
// lgkm waits); PIN; [vmcnt]; BAR}. The end-of-phase barrier is load-bearing
// for WAR (reads of buffer X complete -- via MFMA-use waits pinned by
// sched_barrier(0) -- before any wave restages X after the barrier).
// Drains: end of A2/B2, vmcnt(3) (7 outstanding, oldest 4 = prev tile done).
// ---------------------------------------------------------------------------
#define SAU(bufi, u, kt) \
  GLD_LDS16(A + abase + (uint64_t)(u) * 65536 + (uint64_t)(kt) * 64, \
            (char*)Asp[bufi] + (u) * 8192 + ldst)
#define SBU(bufi, u, kt) \
  GLD_LDS16(Bt + bbase + (uint64_t)(u) * 65536 + (uint64_t)(kt) * 64, \
            (char*)Bsp[bufi] + (u) * 8192 + ldst)

#define RDA2(bufi, mb) do { \
    const char* _p = (const char*)Asp[bufi] + (wm * 64 + (mb) * 16 + l16) * 128; \
    af[0][0] = *(const bf16x8*)(_p + pcb0); \
    af[0][1] = *(const bf16x8*)(_p + pcb1); \
    af[1][0] = *(const bf16x8*)(_p + 2048 + pcb0); \
    af[1][1] = *(const bf16x8*)(_p + 2048 + pcb1); \
  } while (0)

#define RDB6(bufi) do { \
    const char* _p = (const char*)Bsp[bufi] + (wn * 96 + l16) * 128; \
    _Pragma("unroll") for (int _j = 0; _j < 6; ++_j) { \
      bfr[_j][0] = *(const bf16x8*)(_p + _j * 2048 + pcb0); \
      bfr[_j][1] = *(const bf16x8*)(_p + _j * 2048 + pcb1); \
    } \
  } while (0)

#define MMQ24(mb) do { \
    _Pragma("unroll") for (int _i = 0; _i < 2; ++_i) \
      _Pragma("unroll") for (int _j = 0; _j < 6; ++_j) \
        _Pragma("unroll") for (int _k = 0; _k < 2; ++_k) \
          acc[(mb) + _i][_j] = __builtin_amdgcn_mfma_f32_16x16x32_bf16( \
              af[_i][_k], bfr[_j][_k], acc[(mb) + _i][_j], 0, 0, 0); \
  } while (0)

__global__ __launch_bounds__(512, 2) void gemm_qkv_8ph(
    const bf16* __restrict__ A, const bf16* __restrict__ Bt,
    const float* __restrict__ b0, const float* __restrict__ b1, const float* __restrict__ b2,
    __half* __restrict__ qkv) {
  const int t    = threadIdx.x;
  const int m0   = blockIdx.x * 256;
  const int n0   = blockIdx.y * 192;
  const int lane = t & 63;
  const int wave = t >> 6;      // 0..7
  const int wm   = wave >> 1;   // 0..3 -> 64-row strip
  const int wn   = wave & 1;    // 0..1 -> 96-col strip
  const int quad = lane >> 4;
  const int l16  = lane & 15;

  // A dbuf 2x32KB @0, B dbuf 2x24KB @65536; epilogue reuses all 112KB.
  __shared__ alignas(16) char smem[114688];
  bf16* const Asp[2] = {(bf16*)smem, (bf16*)(smem + 32768)};
  bf16* const Bsp[2] = {(bf16*)(smem + 65536), (bf16*)(smem + 90112)};

  // staging: thread t -> linear LDS slot (row = srt within 64-row unit,
  // chunk = t&7); global source pre-swizzled: chunk ^= row&7.
  const int srt = t >> 3;
  const int sct = ((t & 7) ^ (srt & 7)) << 3;
  const uint64_t abase = (uint64_t)(m0 + srt) * 1024 + sct;
  const uint64_t bbase = (uint64_t)(n0 + srt) * 1024 + sct;
  const int ldst = t * 16;

  const int pcb0 = ((quad) ^ (l16 & 7)) << 4;
  const int pcb1 = ((4 + quad) ^ (l16 & 7)) << 4;

  floatx4 acc[4][6];
#pragma unroll
  for (int i = 0; i < 4; ++i)
#pragma unroll
    for (int j = 0; j < 6; ++j) {
      floatx4 z = {0.f, 0.f, 0.f, 0.f};
      acc[i][j] = z;
    }
  bf16x8 af[2][2], bfr[6][2];

  // prologue: t0 full (7 units) -> buf0; t1.B (3 units) -> buf1.
  SBU(0, 0, 0); SBU(0, 1, 0); SBU(0, 2, 0);
  SAU(0, 0, 0); SAU(0, 1, 0); SAU(0, 2, 0); SAU(0, 3, 0);
  SBU(1, 0, 1); SBU(1, 1, 1); SBU(1, 2, 1);
  asm volatile("s_waitcnt vmcnt(3)" ::: "memory");  // t0's 7 arrived
  BAR();

  for (int i = 0; i < 8; ++i) {
    const int kt1 = 2 * i + 1;
    const int kt2 = 2 * i + 2;
    const int kt3 = 2 * i + 3;
    const bool pf = (i < 7);

    // A1: read buf0 A[mb0-1]+B(all); stage buf1.A0-3 (t1; free since prev B2)
    RDA2(0, 0); RDB6(0);
    SAU(1, 0, kt1); SAU(1, 1, kt1); SAU(1, 2, kt1); SAU(1, 3, kt1);
    __builtin_amdgcn_s_setprio(1); MMQ24(0); __builtin_amdgcn_s_setprio(0);
    PIN();
    BAR();

    // A2: read buf0 A[mb2-3]; stage buf0.B0-2 (t2; free after A1); drain t1
    RDA2(0, 2);
    if (pf) { SBU(0, 0, kt2); SBU(0, 1, kt2); SBU(0, 2, kt2); }
    __builtin_amdgcn_s_setprio(1); MMQ24(2); __builtin_amdgcn_s_setprio(0);
    PIN();
    if (pf) { asm volatile("s_waitcnt vmcnt(3)" ::: "memory"); }
    else    { asm volatile("s_waitcnt vmcnt(0)" ::: "memory"); }
    BAR();

    // B1: read buf1 A[mb0-1]+B(all); stage buf0.A0-3 (t2; free after A2)
    RDA2(1, 0); RDB6(1);
    if (pf) { SAU(0, 0, kt2); SAU(0, 1, kt2); SAU(0, 2, kt2); SAU(0, 3, kt2); }
    __builtin_amdgcn_s_setprio(1); MMQ24(0); __builtin_amdgcn_s_setprio(0);
    PIN();
    BAR();

    // B2: read buf1 A[mb2-3]; stage buf1.B0-2 (t3; free after B1); drain t2
    RDA2(1, 2);
    if (pf) { SBU(1, 0, kt3); SBU(1, 1, kt3); SBU(1, 2, kt3); }
    __builtin_amdgcn_s_setprio(1); MMQ24(2); __builtin_amdgcn_s_setprio(0);
    PIN();
    if (pf) { asm volatile("s_waitcnt vmcnt(3)" ::: "memory"); }
    BAR();
  }

  // epilogue: bias + f16; single LDS restage (256 rows x stride 200 halves =
  // 100KB over smem), one barrier, then 12 coalesced f16x8 stores per thread.
  float bvs[6];
#pragma unroll
  for (int nj = 0; nj < 6; ++nj) {
    const int n = n0 + wn * 96 + nj * 16 + l16;
    const int which = n >> 10;
    const int c = n & 1023;
    bvs[nj] = ((which == 0) ? b0 : (which == 1) ? b1 : b2)[c];
  }
  _Float16* stg = (_Float16*)smem;
#pragma unroll
  for (int mb = 0; mb < 4; ++mb)
#pragma unroll
    for (int nj = 0; nj < 6; ++nj)
#pragma unroll
      for (int r = 0; r < 4; ++r)
        stg[(wm * 64 + mb * 16 + quad * 4 + r) * 200 + wn * 96 + nj * 16 + l16] =
            (_Float16)(acc[mb][nj][r] + bvs[nj]);
  BAR();
#pragma unroll
  for (int rep = 0; rep < 12; ++rep) {
    const int cc = t + rep * 512;     // 0..6143 = 256 rows x 24 chunks
    const int rl = cc / 24;
    const int ch = cc - rl * 24;
    const f16x8 v = *(const f16x8*)(stg + rl * 200 + ch * 8);
    *(f16x8*)((_Float16*)qkv + (size_t)(m0 + rl) * 3072 + n0 + ch * 8) = v;
  }
}

// ---------------------------------------------------------------------------
// Projection GEMM — 128x128 m97 structure. A row-major (8192,1024) bf16
// (attn output); Bt = Wo^T; out fp32 + bias.
// ---------------------------------------------------------------------------
__global__ __launch_bounds__(256) void gemm_proj(
    const bf16* __restrict__ A, const bf16* __restrict__ Bt,
    const float* __restrict__ bias, float* __restrict__ fout) {
  const int tid  = threadIdx.x;
  const int m0   = blockIdx.x * 128;
  const int n0   = blockIdx.y * 128;
  const int lane = tid & 63;
  const int wave = tid >> 6;
  const int wr   = (wave >> 1) * 64;
  const int wc   = (wave & 1) * 64;
  const int quad = lane >> 4;
  const int l16  = lane & 15;

  __shared__ alignas(16) bf16 As[128 * 64];
  __shared__ alignas(16) bf16 Bs[128 * 64];

  const int srow = tid >> 3;
  const int cg   = (tid & 7) ^ (srow & 7);
  const uint64_t aoff = (uint64_t)(m0 + srow) * 1024 + cg * 8;
  const uint64_t boff = (uint64_t)(n0 + srow) * 1024 + cg * 8;

  floatx4 acc[4][4];
#pragma unroll
  for (int i = 0; i < 4; ++i)
#pragma unroll
    for (int j = 0; j < 4; ++j) {
      floatx4 z = {0.f, 0.f, 0.f, 0.f};
      acc[i][j] = z;
    }

  for (int k0 = 0; k0 < 1024; k0 += 64) {
    __syncthreads();
#pragma unroll
    for (int it = 0; it < 4; ++it) {
      GLD_LDS16(A + aoff + (uint64_t)it * 32768 + k0, (char*)As + it * 4096 + tid * 16);
      GLD_LDS16(Bt + boff + (uint64_t)it * 32768 + k0, (char*)Bs + it * 4096 + tid * 16);
    }
    __syncthreads();

#pragma unroll
    for (int kc = 0; kc < 2; ++kc) {
      bf16x8 af[4], bfr[4];
#pragma unroll
      for (int i = 0; i < 4; ++i) {
        const int mrow = wr + i * 16 + l16;
        const int pca  = (kc * 4 + quad) ^ (mrow & 7);
        af[i] = *(const bf16x8*)(As + mrow * 64 + pca * 8);
        const int nrow = wc + i * 16 + l16;
        const int pcb  = (kc * 4 + quad) ^ (nrow & 7);
        bfr[i] = *(const bf16x8*)(Bs + nrow * 64 + pcb * 8);
      }
#pragma unroll
      for (int i = 0; i < 4; ++i)
#pragma unroll
        for (int j = 0; j < 4; ++j)
          acc[i][j] = __builtin_amdgcn_mfma_f32_16x16x32_bf16(af[i], bfr[j], acc[i][j], 0, 0, 0);
    }
  }

#pragma unroll
  for (int i = 0; i < 4; ++i)
#pragma unroll
    for (int j = 0; j < 4; ++j)
#pragma unroll
      for (int r = 0; r < 4; ++r) {
        const int m = m0 + wr + i * 16 + quad * 4 + r;
        const int n = n0 + wc + j * 16 + l16;
        fout[(uint64_t)m * 1024 + n] = acc[i][j][r] + bias[n];
      }
}

// ---------------------------------------------------------------------------
// Dilated attention — MFMA. Reads Q/K/V from row-major qkv (B,N,3072) f16;
// writes attn output row-major (B,N,1024) bf16.
// ---------------------------------------------------------------------------
#define RMAXA 32
#define VTS 176       // VT col stride (halves)
#define PS  104       // P row stride (halves)

__global__ __launch_bounds__(256) void dilated_attn_mfma_kernel(
    const __half* __restrict__ qkv, bf16* __restrict__ attn_out,
    const int* __restrict__ kptr, const int* __restrict__ dptr) {
  const int tid  = threadIdx.x;
  const int wave = tid >> 6, lane = tid & 63;
  const int quad = lane >> 4, l16 = lane & 15;
  const int bh = blockIdx.x >> 5;       // 32 query-blocks of 64 per (b,h)
  const int Q0 = (blockIdx.x & 31) * 64;
  const int b  = bh >> 4, h = bh & 15;
  const int kk  = kptr[0];
  const int dil = dptr[0];
  const int R   = kk * dil;
  const size_t xb = (size_t)b * 2048;
  const int qo = h * 64, ko = 1024 + h * 64, vo = 2048 + h * 64;
  const _Float16* Xh = (const _Float16*)qkv;

  __shared__ alignas(16) _Float16 smem[64 * VTS + 4 * 16 * PS];  // 35840 B
  _Float16* VT = smem;
  _Float16* Pw = smem + 64 * VTS + wave * 16 * PS;

  const bool fast = (R <= RMAXA) && (dil >= 1);

  if (fast) {
    // zero-fill VT + P (guards / pad cols must be 0, not stale/NaN bits)
    {
      const int nch = (64 * VTS + 4 * 16 * PS) / 8;
      const f16x8 z = {0, 0, 0, 0, 0, 0, 0, 0};
      for (int c = tid; c < nch; c += 256) ((f16x8*)smem)[c] = z;
    }
    __syncthreads();

    // stage V transposed: VT[dh][col], col = j - (Q0-R) + 32
    const int jlo = Q0 - R;  // unclamped
    const int lo = (jlo > 0) ? jlo : 0;
    const int hi = (Q0 + 63 + R < 2047) ? Q0 + 63 + R : 2047;
    const int nrows = hi - lo + 1;
    for (int idx = tid; idx < nrows * 8; idx += 256) {
      const int r = idx >> 3, c = idx & 7;
      const int j = lo + r;
      const f16x8 v = *(const f16x8*)(Xh + (xb + j) * 3072 + vo + c * 8);
      const int col = j - jlo + 32;
#pragma unroll
      for (int s = 0; s < 8; ++s) VT[(c * 8 + s) * VTS + col] = v[s];
    }
    __syncthreads();

    const int i0 = Q0 + wave * 16;
    // Q A-frags (2 k-chunks of 32 over DH=64)
    const f16x8 a0 = *(const f16x8*)(Xh + (xb + i0 + l16) * 3072 + qo + quad * 8);
    const f16x8 a1 = *(const f16x8*)(Xh + (xb + i0 + l16) * 3072 + qo + 32 + quad * 8);

    const int nkt = (16 + 2 * R + 15) >> 4;   // key tiles of 16
    const int jw0 = i0 - R;                   // wave key-window start
    float lsum[4] = {0.f, 0.f, 0.f, 0.f};
    const floatx4 zf = {0.f, 0.f, 0.f, 0.f};

    for (int kt = 0; kt < nkt; ++kt) {
      const int j0 = jw0 + 16 * kt;
      const int jn = j0 + l16;                        // this lane's key
      const int jc = (jn < 0) ? 0 : (jn > 2047 ? 2047 : jn);
      const f16x8 k0v = *(const f16x8*)(Xh + (xb + jc) * 3072 + ko + quad * 8);
      const f16x8 k1v = *(const f16x8*)(Xh + (xb + jc) * 3072 + ko + 32 + quad * 8);
      floatx4 s4 = __builtin_amdgcn_mfma_f32_16x16x32_f16(a0, k0v, zf, 0, 0, 0);
      s4 = __builtin_amdgcn_mfma_f32_16x16x32_f16(a1, k1v, s4, 0, 0, 0);
#pragma unroll
      for (int r = 0; r < 4; ++r) {
        const int m = quad * 4 + r;
        const int d = jn - (i0 + m);
        const bool valid = ((unsigned)jn < 2048u) && (d >= -R) && (d <= R) && (d % dil == 0);
        const float pe = valid ? __expf(s4[r] * 0.125f) : 0.f;
        lsum[r] += pe;
        Pw[m * PS + kt * 16 + l16] = (_Float16)pe;
      }
    }
    // row sums: reduce across the 16 lanes of each quad
#pragma unroll
    for (int r = 0; r < 4; ++r) {
      lsum[r] += __shfl_xor(lsum[r], 1);
      lsum[r] += __shfl_xor(lsum[r], 2);
      lsum[r] += __shfl_xor(lsum[r], 4);
      lsum[r] += __shfl_xor(lsum[r], 8);
    }

    // PV: o[t](16 x 16dh) accumulated f32; A = P[m=lane&15][k], B = VT
    const int nkc = (nkt * 16 + 31) >> 5;     // 32-wide k-chunks
    floatx4 o[4] = {zf, zf, zf, zf};
    const int vbase = 16 * wave + 32;         // VT col of k_rel = 0
    for (int c = 0; c < nkc; ++c) {
      const f16x8 pa = *(const f16x8*)(Pw + l16 * PS + c * 32 + quad * 8);
#pragma unroll
      for (int t = 0; t < 4; ++t) {
        const f16x8 vb = *(const f16x8*)(VT + (t * 16 + l16) * VTS + vbase + c * 32 + quad * 8);
        o[t] = __builtin_amdgcn_mfma_f32_16x16x32_f16(pa, vb, o[t], 0, 0, 0);
      }
    }

    // normalize + stage O into Pw ([m][dh], stride PS), then coalesced store
#pragma unroll
    for (int t = 0; t < 4; ++t) {
#pragma unroll
      for (int r = 0; r < 4; ++r)
        Pw[(quad * 4 + r) * PS + t * 16 + l16] = (_Float16)(o[t][r] / lsum[r]);
    }
    const int orow = lane >> 2, oseg = lane & 3;
#pragma unroll
    for (int hseg = 0; hseg < 2; ++hseg) {
      const f16x8 ov = *(const f16x8*)(Pw + orow * PS + oseg * 16 + hseg * 8);
      bf16 ob[8];
#pragma unroll
      for (int s = 0; s < 8; ++s) ob[s] = (bf16)(float)ov[s];
      *(uint4*)(attn_out + (xb + i0 + orow) * 1024 + h * 64 + oseg * 16 + hseg * 8) =
          *(const uint4*)ob;
    }
    return;
  }

  // ---- fallback: rarely taken; plain per-lane scalar loop ----
  if (tid < 64) {
    const int i = Q0 + tid;
    float l = 0.f;
    float oacc[64];
#pragma unroll
    for (int u = 0; u < 64; ++u) oacc[u] = 0.f;
    float qv[64];
#pragma unroll
    for (int u = 0; u < 64; ++u) qv[u] = (float)Xh[(xb + i) * 3072 + qo + u];
    for (int tt = -kk; tt <= kk; ++tt) {
      const int j = i + (int)((long long)tt * dil);
      if (j < 0 || j >= 2048) continue;
      float s = 0.f;
      for (int u = 0; u < 64; ++u) s += qv[u] * (float)Xh[(xb + j) * 3072 + ko + u];
      const float pe = __expf(s * 0.125f);
      l += pe;
      for (int u = 0; u < 64; ++u) oacc[u] += pe * (float)Xh[(xb + j) * 3072 + vo + u];
    }
    for (int u = 0; u < 64; ++u)
      attn_out[(xb + i) * 1024 + h * 64 + u] = (bf16)(oacc[u] / l);
  }
}

// ---------------------------------------------------------------------------
extern "C" void kernel_launch(void* const* d_in, const int* in_sizes, int n_in,
                              void* d_out, int out_size, void* d_ws, size_t ws_size,
                              hipStream_t stream) {
  const float* x  = (const float*)d_in[0];
  const float* Wq = (const float*)d_in[1];
  const float* bq = (const float*)d_in[2];
  const float* Wk = (const float*)d_in[3];
  const float* bk = (const float*)d_in[4];
  const float* Wv = (const float*)d_in[5];
  const float* bv = (const float*)d_in[6];
  const float* Wo = (const float*)d_in[7];
  const float* bo = (const float*)d_in[8];
  const int* kp   = (const int*)d_in[9];
  const int* dp   = (const int*)d_in[10];
  float* out = (float*)d_out;

  bf16*   xbf   = (bf16*)d_ws;                   // 8388608  (B,N,D) bf16
  bf16*   WTqkv = xbf + 8388608;                 // 3072*1024 bf16
  bf16*   WoT   = WTqkv + 3072 * 1024;           // 1024*1024 bf16
  __half* qkv   = (__half*)(WoT + 1024 * 1024);  // 8192*3072 f16 row-major
  bf16*   attnO = xbf;                           // alias: (B,N,1024) bf16

  prep_kernel<<<dim3(3072), 256, 0, stream>>>(x, Wq, Wk, Wv, Wo, xbf, WTqkv, WoT);

  gemm_qkv_8ph<<<dim3(32, 16), 512, 0, stream>>>(xbf, WTqkv, bq, bk, bv, qkv);

  dilated_attn_mfma_kernel<<<dim3(2048), 256, 0, stream>>>(qkv, attnO, kp, dp);

  gemm_proj<<<dim3(64, 8), 256, 0, stream>>>(attnO, WoT, bo, out);
}